// Round 9
// baseline (1942.243 us; speedup 1.0000x reference)
//
#include <hip/hip_runtime.h>

typedef _Float16 h2v __attribute__((ext_vector_type(2)));
typedef _Float16 h4v __attribute__((ext_vector_type(4)));
typedef _Float16 h8v __attribute__((ext_vector_type(8)));
typedef float    f4v __attribute__((ext_vector_type(4)));
typedef unsigned int u32;
typedef unsigned long long u64;

#define WUP_STRIDE 264        // wup padded row (halves)
#define NBATCH 2

// LDS layout (bytes) for fused_k  (total 55296 -> 2 blocks/CU)
#define WT_STRIDE 264         // halves per w-tile row (528 B: 2-way banks, free)
#define WT0_OFF   0
#define WT1_OFF   16896       // 32*264*2
#define TT_OFF    33792       // 256 rows * 36 halves * 2 = 18432
#define TT_STRIDE 36          // halves per Tt row (72 B)
#define GC_STRIDE 268         // halves per G-chunk row (536 B); 32*536=17152 <= 18432
#define P_OFF     52224
#define HS_OFF    54272
#define CS_OFF    54784
#define LDS_FUSED 55296

__device__ inline f4v mfma16(h8v a, h8v b, f4v c) {
  return __builtin_amdgcn_mfma_f32_16x16x32_f16(a, b, c, 0, 0, 0);
}

__device__ inline float dot2f(u32 a, u32 b, float c) {
#if __has_builtin(__builtin_amdgcn_fdot2)
  return __builtin_amdgcn_fdot2(__builtin_bit_cast(h2v, a), __builtin_bit_cast(h2v, b), c, false);
#else
  h2v av = __builtin_bit_cast(h2v, a), bv = __builtin_bit_cast(h2v, b);
  return c + (float)av[0] * (float)bv[0] + (float)av[1] * (float)bv[1];
#endif
}

__device__ inline h8v cvt8(f4v lo, f4v hi) {
  h8v d;
  d[0] = (_Float16)lo[0]; d[1] = (_Float16)lo[1]; d[2] = (_Float16)lo[2]; d[3] = (_Float16)lo[3];
  d[4] = (_Float16)hi[0]; d[5] = (_Float16)hi[1]; d[6] = (_Float16)hi[2]; d[7] = (_Float16)hi[3];
  return d;
}

// raw barrier: LDS-visibility only, never drains vmcnt (keeps prefetch alive)
#define BAR() { asm volatile("s_waitcnt lgkmcnt(0)" ::: "memory"); \
                __builtin_amdgcn_s_barrier(); \
                asm volatile("" ::: "memory"); }

// fragment loader: ROW-BASE pointer; kk/g offsets applied exactly once
#define LDH(basep, kk, dst) { \
    h4v lo_ = *(const h4v*)((basep) + (kk)*32 + 4*g); \
    h4v hi_ = *(const h4v*)((basep) + (kk)*32 + 16 + 4*g); \
    dst = __builtin_shufflevector(lo_, hi_, 0, 1, 2, 3, 4, 5, 6, 7); }

// ---- prep: Wu padded row-major (for recurrence row pulls) ----
__global__ void prep_k(const float* __restrict__ Wu, _Float16* __restrict__ wup)
{
  int j = blockIdx.x, k = threadIdx.x;
  wup[j * WUP_STRIDE + k] = (_Float16)Wu[j * 256 + k];
  if (k < 8) wup[j * WUP_STRIDE + 256 + k] = (_Float16)0.f;
}

// ---- prep2: pack Wv (wvp) and Ww (wwp2, t-sliced) into MFMA B-frag order ----
// koff(g,h) = h<4 ? 4g+h : 16+4g+(h-4)
// wvp [(nt*8+kk)*64+lane]*8+h  = Wv[kk*32+koff][nt*16+l15]
// wwp2[(tau*16+it)*64+lane]*8+h = Ww[it*16+l15][tau*32+koff]
__global__ void prep2_k(const float* __restrict__ Wv, const float* __restrict__ Ww,
                        _Float16* __restrict__ wvp, _Float16* __restrict__ wwp2)
{
  int b = blockIdx.x;
  int tid = threadIdx.x;
  int lane = tid & 63, q = tid >> 6;
  int g2 = (lane >> 4) & 3, l15 = lane & 15;
  if (b < 128) {
    int nt = b >> 3, kk = b & 7;
    int j = nt * 16 + l15;
    _Float16* dst = wvp + ((size_t)(b * 64 + lane)) * 8;
#pragma unroll
    for (int e = 0; e < 2; ++e) {
      int h = 2 * q + e;
      int k = kk * 32 + (h < 4 ? 4 * g2 + h : 16 + 4 * g2 + (h - 4));
      dst[h] = (_Float16)Wv[(size_t)k * 256 + j];
    }
  } else {
    int s = b - 128;                 // tau*16 + it
    int it = s & 15;
    int tau = s >> 4;
    int i = it * 16 + l15;
    _Float16* dst = wwp2 + ((size_t)(s * 64 + lane)) * 8;
#pragma unroll
    for (int e = 0; e < 2; ++e) {
      int h = 2 * q + e;
      int t = tau * 32 + (h < 4 ? 4 * g2 + h : 16 + 4 * g2 + (h - 4));
      dst[h] = (_Float16)Ww[(size_t)i * 256 + t];
    }
  }
}

// out[b,i] = sum_j M[i,j] * V[b,j]   (beta = Ww@b ; final x = Wv@c)
__global__ void matvec_k(const float* __restrict__ M, const float* __restrict__ V,
                         float* __restrict__ out)
{
  __shared__ float vb[256];
  int b = blockIdx.x, i = threadIdx.x;
  vb[i] = V[(size_t)b * 256 + i];
  __syncthreads();
  float a0 = 0.f;
#pragma unroll 8
  for (int j = 0; j < 256; j += 4) {
    f4v m = *(const f4v*)(M + (size_t)i * 256 + j);
    a0 += m[0] * vb[j] + m[1] * vb[j + 1] + m[2] * vb[j + 2] + m[3] * vb[j + 3];
  }
  out[(size_t)b * 256 + i] = a0;
}

// ================= fused: T-tile streaming + G accumulation + recurrence ====
// Per batch, tau = 0..7 (32 t-rows each), ONE barrier per tau:
//   write wt[next] from staged regs; issue w loads for tau+2;
//   GEMM1: T[tau] = w_tile @ Wv   (A = wt LDS, B = wvp L2)  -> TT (wave-local)
//   GEMM2: G += Ww[:,tau] @ T[tau] (A = TT LDS, B = wwp2 L2) -> acc2
// Then G-bounce (8 chunks through TT region) + 20-step recurrence.
__global__ __launch_bounds__(512, 4) void fused_k(
    const float* __restrict__ w, const _Float16* __restrict__ wvp,
    const _Float16* __restrict__ wwp2, const _Float16* __restrict__ wup,
    const float* __restrict__ beta, float* __restrict__ cout)
{
  extern __shared__ char smem[];
  _Float16* const TT = (_Float16*)(smem + TT_OFF);
  float*    const P  = (float*)(smem + P_OFF);
  _Float16* const HS = (_Float16*)(smem + HS_OFF);
  _Float16* const CS = (_Float16*)(smem + CS_OFF);

  const int tid = threadIdx.x;
  const int wv = tid >> 6, lane = tid & 63;
  const int g = (lane >> 4) & 3, l15 = lane & 15;
  const int st_t = tid >> 4;            // staging row 0..31
  const int st_c = (tid & 15) << 4;     // staging col base
  const int i_r = tid & 255;            // recurrence row
  const int h2  = tid >> 8;

  f4v sw[4];                            // staged w (next-next tile)

  for (int bi = 0; bi < NBATCH; ++bi) {
    const int B = blockIdx.x * NBATCH + bi;
    const float* wb = w + (size_t)B * 65536;
    const int Bn = (B + 1 < 2048) ? (B + 1) : B;
    const float* wbn = w + (size_t)Bn * 65536;

    if (bi == 0) {
      // prologue: tile0 -> wt[0]; stage tile1 into regs
      const float* src0 = wb + st_t * 256 + st_c;
#pragma unroll
      for (int q = 0; q < 4; ++q) sw[q] = *(const f4v*)(src0 + q * 4);
      {
        _Float16* dst = (_Float16*)(smem + WT0_OFF) + st_t * WT_STRIDE + st_c;
        *(h8v*)dst = cvt8(sw[0], sw[1]);
        *(h8v*)(dst + 8) = cvt8(sw[2], sw[3]);
      }
      const float* src1 = wb + (32 + st_t) * 256 + st_c;
#pragma unroll
      for (int q = 0; q < 4; ++q) sw[q] = *(const f4v*)(src1 + q * 4);
      BAR();
    }

    f4v acc2[2][16];
#pragma unroll
    for (int jt = 0; jt < 2; ++jt)
#pragma unroll
      for (int it = 0; it < 16; ++it) acc2[jt][it] = f4v{0.f, 0.f, 0.f, 0.f};

#pragma unroll 2
    for (int tau = 0; tau < 8; ++tau) {
      // A) write wt[(tau+1)&1] from staged regs (buffer not read this tau)
      {
        _Float16* dst = (_Float16*)(smem + (((tau + 1) & 1) ? WT1_OFF : WT0_OFF))
                        + st_t * WT_STRIDE + st_c;
        *(h8v*)dst = cvt8(sw[0], sw[1]);
        *(h8v*)(dst + 8) = cvt8(sw[2], sw[3]);
      }
      // B) issue w loads for tau+2 (skip past-the-end on last batch)
      {
        const int tld = tau + 2;
        if (bi == 0 || tld <= 7) {
          const float* src = (tld <= 7)
              ? (wb  + (size_t)(tld * 32 + st_t) * 256 + st_c)
              : (wbn + (size_t)((tld - 8) * 32 + st_t) * 256 + st_c);
#pragma unroll
          for (int q = 0; q < 4; ++q) sw[q] = *(const f4v*)(src + q * 4);
        }
      }
      // C) GEMM1(tau): T fragments (A = wt[cur], B = wvp from L2)
      f4v acc1[2][2];
#pragma unroll
      for (int a = 0; a < 2; ++a)
#pragma unroll
        for (int b2 = 0; b2 < 2; ++b2) acc1[a][b2] = f4v{0.f, 0.f, 0.f, 0.f};
      {
        const _Float16* wt = (const _Float16*)(smem + ((tau & 1) ? WT1_OFF : WT0_OFF));
#pragma unroll
        for (int kk = 0; kk < 8; ++kk) {
          h8v a0, a1;
          LDH(wt + (l15) * WT_STRIDE, kk, a0);
          LDH(wt + (16 + l15) * WT_STRIDE, kk, a1);
#pragma unroll
          for (int jn = 0; jn < 2; ++jn) {
            const int JN = wv * 2 + jn;
            h8v bf = *(const h8v*)(wvp + ((size_t)(JN * 8 + kk) * 64 + lane) * 8);
            acc1[0][jn] = mfma16(a0, bf, acc1[0][jn]);
            acc1[1][jn] = mfma16(a1, bf, acc1[1][jn]);
          }
        }
      }
      // D) write Tt(tau) — wave-local rows, no barrier needed before E
#pragma unroll
      for (int tm = 0; tm < 2; ++tm)
#pragma unroll
        for (int jn = 0; jn < 2; ++jn) {
          const int j = wv * 32 + jn * 16 + l15;
          f4v a = acc1[tm][jn];
          h4v t4; t4[0] = (_Float16)a[0]; t4[1] = (_Float16)a[1];
          t4[2] = (_Float16)a[2]; t4[3] = (_Float16)a[3];
          *(h4v*)(TT + j * TT_STRIDE + tm * 16 + g * 4) = t4;
        }
      // E) GEMM2(tau): G += Tt * Ww  (A = TT wave-local, B = wwp2 from L2)
      {
        h8v a0, a1;
        LDH(TT + (wv * 32 + l15) * TT_STRIDE, 0, a0);
        LDH(TT + (wv * 32 + 16 + l15) * TT_STRIDE, 0, a1);
        const _Float16* wws = wwp2 + (size_t)tau * 8192;
#pragma unroll
        for (int it = 0; it < 16; ++it) {
          h8v bf = *(const h8v*)(wws + ((size_t)(it * 64 + lane)) * 8);
          acc2[0][it] = mfma16(a0, bf, acc2[0][it]);
          acc2[1][it] = mfma16(a1, bf, acc2[1][it]);
        }
      }
      // F) one barrier per tau (orders wt[next] writes vs next-tau reads)
      BAR();
    } // tau

    // ---- G bounce: 8 chunks of 32 i-rows through TT region ----
    uint4 gq[16];
    _Float16* const GC = TT;   // stride GC_STRIDE halves
#pragma unroll
    for (int c = 0; c < 8; ++c) {
#pragma unroll
      for (int jt = 0; jt < 2; ++jt)
#pragma unroll
        for (int e = 0; e < 2; ++e) {
          const int IT = 2 * c + e;
          const int il = e * 16 + l15;                 // i - c*32
          const int j  = wv * 32 + jt * 16 + g * 4;
          f4v a = acc2[jt][IT];
          h4v t4; t4[0] = (_Float16)a[0]; t4[1] = (_Float16)a[1];
          t4[2] = (_Float16)a[2]; t4[3] = (_Float16)a[3];
          *(h4v*)(GC + il * GC_STRIDE + j) = t4;       // row il, cols j..j+3
        }
      BAR();
      if ((i_r >> 5) == c) {
        const int il = i_r & 31;
        const char* row = (const char*)(GC + il * GC_STRIDE) + h2 * 256;
#pragma unroll
        for (int q = 0; q < 16; ++q) {
          u64 lo = *(const u64*)(row + q * 16);
          u64 hi = *(const u64*)(row + q * 16 + 8);
          uint4 v;
          ((u64*)&v)[0] = lo; ((u64*)&v)[1] = hi;
          gq[q] = v;
        }
      }
      BAR();
    }

    // ---- recurrence (proven structure) ----
    uint4 wq[16];
    {
      const uint4* wrow = (const uint4*)(wup + (size_t)i_r * WUP_STRIDE) + h2 * 16;
#pragma unroll
      for (int q = 0; q < 16; ++q) wq[q] = wrow[q];
    }
    float my_beta = beta[(size_t)B * 256 + i_r];

    if (tid < 256) HS[tid] = (_Float16)0.f; else CS[tid - 256] = (_Float16)0.f;
    float cm = 0.f;
    BAR();

    const uint4* hrow = (const uint4*)((const char*)HS + h2 * 256);
    const uint4* crow = (const uint4*)((const char*)CS + h2 * 256);

    for (int t = 0; t < 20; ++t) {
      float au[4] = {0.f, 0.f, 0.f, 0.f};
      float ag[4] = {0.f, 0.f, 0.f, 0.f};
#pragma unroll
      for (int q = 0; q < 16; ++q) {
        uint4 wu4 = wq[q];
        uint4 gg  = gq[q];
        uint4 hv  = hrow[q];
        uint4 cv  = crow[q];
        float a = au[q & 3], e = ag[q & 3];
        a = dot2f(wu4.x, hv.x, a);
        a = dot2f(wu4.y, hv.y, a);
        a = dot2f(wu4.z, hv.z, a);
        a = dot2f(wu4.w, hv.w, a);
        e = dot2f(gg.x, cv.x, e);
        e = dot2f(gg.y, cv.y, e);
        e = dot2f(gg.z, cv.z, e);
        e = dot2f(gg.w, cv.w, e);
        au[q & 3] = a; ag[q & 3] = e;
      }
      float auf = (au[0] + au[1]) + (au[2] + au[3]);
      float agf = (ag[0] + ag[1]) + (ag[2] + ag[3]);
      P[tid] = (auf - agf) * 128.f;   // descale 2^7
      BAR();
      float y = my_beta + P[i_r] + P[i_r + 256];
      float hval = fmaxf(y, 0.f);
      if (h2 == 0) {
        cm += hval;
        HS[i_r] = (_Float16)(hval * 0.0078125f);  // * 2^-7
        CS[i_r] = (_Float16)(cm * 0.0078125f);
      }
      BAR();
    }
    if (h2 == 0) cout[(size_t)B * 256 + i_r] = cm;
    BAR();   // protect LDS before next batch
  } // bi
}

extern "C" void kernel_launch(void* const* d_in, const int* in_sizes, int n_in,
                              void* d_out, int out_size, void* d_ws, size_t ws_size,
                              hipStream_t stream)
{
  const float* w  = (const float*)d_in[0];
  const float* b  = (const float*)d_in[1];
  const float* Ww = (const float*)d_in[2];
  const float* Wu = (const float*)d_in[3];
  const float* Wv = (const float*)d_in[4];

  char* ws = (char*)d_ws;
  float*    beta = (float*)(ws);
  float*    cbuf = (float*)(ws + (size_t)2 * 1024 * 1024);
  _Float16* wvp  = (_Float16*)(ws + (size_t)4 * 1024 * 1024);
  _Float16* wwp2 = (_Float16*)(ws + (size_t)4 * 1024 * 1024 + 131072);
  _Float16* wup  = (_Float16*)(ws + (size_t)4 * 1024 * 1024 + 262144);

  (void)in_sizes; (void)n_in; (void)out_size; (void)ws_size;

  hipFuncSetAttribute((const void*)fused_k,
                      hipFuncAttributeMaxDynamicSharedMemorySize, LDS_FUSED);

  prep_k<<<256, 256, 0, stream>>>(Wu, wup);
  prep2_k<<<256, 256, 0, stream>>>(Wv, Ww, wvp, wwp2);
  matvec_k<<<2048, 256, 0, stream>>>(Ww, b, beta);                  // beta = Ww @ b
  fused_k<<<1024, 512, LDS_FUSED, stream>>>(w, wvp, wwp2, wup, beta, cbuf);
  matvec_k<<<2048, 256, 0, stream>>>(Wv, cbuf, (float*)d_out);      // x = Wv @ c
}

// Round 10
// 862.919 us; speedup vs baseline: 2.2508x; 2.2508x over previous
//
#include <hip/hip_runtime.h>

typedef _Float16 h2v __attribute__((ext_vector_type(2)));
typedef _Float16 h4v __attribute__((ext_vector_type(4)));
typedef _Float16 h8v __attribute__((ext_vector_type(8)));
typedef float    f4v __attribute__((ext_vector_type(4)));
typedef unsigned int u32;
typedef unsigned long long u64;

#define WUP_STRIDE 264        // wup padded row (halves)
#define NBATCH 2

// LDS layout (bytes) for fused_k  (total 55296 -> 2 blocks/CU)
#define WT_STRIDE 264         // halves per w-tile row (528 B: 2-way banks, free)
#define WT0_OFF   0
#define WT1_OFF   16896       // 32*264*2
#define TT_OFF    33792       // 256 rows * 36 halves * 2 = 18432
#define TT_STRIDE 36          // halves per Tt row (72 B)
#define GC_STRIDE 268         // halves per G-chunk row (536 B); 32*536=17152 <= 18432
#define P_OFF     52224
#define HS_OFF    54272
#define CS_OFF    54784
#define LDS_FUSED 55296

__device__ inline f4v mfma16(h8v a, h8v b, f4v c) {
  return __builtin_amdgcn_mfma_f32_16x16x32_f16(a, b, c, 0, 0, 0);
}

__device__ inline float dot2f(u32 a, u32 b, float c) {
#if __has_builtin(__builtin_amdgcn_fdot2)
  return __builtin_amdgcn_fdot2(__builtin_bit_cast(h2v, a), __builtin_bit_cast(h2v, b), c, false);
#else
  h2v av = __builtin_bit_cast(h2v, a), bv = __builtin_bit_cast(h2v, b);
  return c + (float)av[0] * (float)bv[0] + (float)av[1] * (float)bv[1];
#endif
}

__device__ inline h8v cvt8(f4v lo, f4v hi) {
  h8v d;
  d[0] = (_Float16)lo[0]; d[1] = (_Float16)lo[1]; d[2] = (_Float16)lo[2]; d[3] = (_Float16)lo[3];
  d[4] = (_Float16)hi[0]; d[5] = (_Float16)hi[1]; d[6] = (_Float16)hi[2]; d[7] = (_Float16)hi[3];
  return d;
}

// raw barrier: LDS-visibility only, never drains vmcnt (keeps prefetch alive)
#define BAR() { asm volatile("s_waitcnt lgkmcnt(0)" ::: "memory"); \
                __builtin_amdgcn_s_barrier(); \
                asm volatile("" ::: "memory"); }

// fragment loader: ROW-BASE pointer; kk/g offsets applied exactly once
#define LDH(basep, kk, dst) { \
    h4v lo_ = *(const h4v*)((basep) + (kk)*32 + 4*g); \
    h4v hi_ = *(const h4v*)((basep) + (kk)*32 + 16 + 4*g); \
    dst = __builtin_shufflevector(lo_, hi_, 0, 1, 2, 3, 4, 5, 6, 7); }

// ---- prep: Wu padded row-major (for recurrence row pulls) ----
__global__ void prep_k(const float* __restrict__ Wu, _Float16* __restrict__ wup)
{
  int j = blockIdx.x, k = threadIdx.x;
  wup[j * WUP_STRIDE + k] = (_Float16)Wu[j * 256 + k];
  if (k < 8) wup[j * WUP_STRIDE + 256 + k] = (_Float16)0.f;
}

// ---- prep2: pack Wv (wvp) and Ww (wwp2, t-sliced) into MFMA B-frag order ----
// koff(g,h) = h<4 ? 4g+h : 16+4g+(h-4)
// wvp [(nt*8+kk)*64+lane]*8+h  = Wv[kk*32+koff][nt*16+l15]
// wwp2[(tau*16+it)*64+lane]*8+h = Ww[it*16+l15][tau*32+koff]
__global__ void prep2_k(const float* __restrict__ Wv, const float* __restrict__ Ww,
                        _Float16* __restrict__ wvp, _Float16* __restrict__ wwp2)
{
  int b = blockIdx.x;
  int tid = threadIdx.x;
  int lane = tid & 63, q = tid >> 6;
  int g2 = (lane >> 4) & 3, l15 = lane & 15;
  if (b < 128) {
    int nt = b >> 3, kk = b & 7;
    int j = nt * 16 + l15;
    _Float16* dst = wvp + ((size_t)(b * 64 + lane)) * 8;
#pragma unroll
    for (int e = 0; e < 2; ++e) {
      int h = 2 * q + e;
      int k = kk * 32 + (h < 4 ? 4 * g2 + h : 16 + 4 * g2 + (h - 4));
      dst[h] = (_Float16)Wv[(size_t)k * 256 + j];
    }
  } else {
    int s = b - 128;                 // tau*16 + it
    int it = s & 15;
    int tau = s >> 4;
    int i = it * 16 + l15;
    _Float16* dst = wwp2 + ((size_t)(s * 64 + lane)) * 8;
#pragma unroll
    for (int e = 0; e < 2; ++e) {
      int h = 2 * q + e;
      int t = tau * 32 + (h < 4 ? 4 * g2 + h : 16 + 4 * g2 + (h - 4));
      dst[h] = (_Float16)Ww[(size_t)i * 256 + t];
    }
  }
}

// out[b,i] = sum_j M[i,j] * V[b,j]   (beta = Ww@b ; final x = Wv@c)
__global__ void matvec_k(const float* __restrict__ M, const float* __restrict__ V,
                         float* __restrict__ out)
{
  __shared__ float vb[256];
  int b = blockIdx.x, i = threadIdx.x;
  vb[i] = V[(size_t)b * 256 + i];
  __syncthreads();
  float a0 = 0.f;
#pragma unroll 8
  for (int j = 0; j < 256; j += 4) {
    f4v m = *(const f4v*)(M + (size_t)i * 256 + j);
    a0 += m[0] * vb[j] + m[1] * vb[j + 1] + m[2] * vb[j + 2] + m[3] * vb[j + 3];
  }
  out[(size_t)b * 256 + i] = a0;
}

// ================= fused: T-tile streaming + G accumulation + recurrence ====
// Per batch, tau = 0..7 (32 t-rows each), ONE barrier per tau:
//   write wt[next] from staged regs; issue w loads for tau+2;
//   GEMM1: T[tau] = w_tile @ Wv   (A = wt LDS, B = wvp L2)  -> TT (wave-local)
//   GEMM2: G += Ww[:,tau] @ T[tau] (A = TT LDS, B = wwp2 L2) -> acc2
// Then G-bounce (8 chunks through TT region) + 20-step recurrence.
// NOTE launch_bounds: hipcc follows CUDA semantics -- 2nd arg is min BLOCKS
// per CU. (512,2) => 16 waves/CU => 128-VGPR cap (no spill, round-8-proven).
// (512,4) forced a 64-VGPR cap and spilled acc2 -> 3.7GB scratch traffic (r9).
__global__ __launch_bounds__(512, 2) void fused_k(
    const float* __restrict__ w, const _Float16* __restrict__ wvp,
    const _Float16* __restrict__ wwp2, const _Float16* __restrict__ wup,
    const float* __restrict__ beta, float* __restrict__ cout)
{
  extern __shared__ char smem[];
  _Float16* const TT = (_Float16*)(smem + TT_OFF);
  float*    const P  = (float*)(smem + P_OFF);
  _Float16* const HS = (_Float16*)(smem + HS_OFF);
  _Float16* const CS = (_Float16*)(smem + CS_OFF);

  const int tid = threadIdx.x;
  const int wv = tid >> 6, lane = tid & 63;
  const int g = (lane >> 4) & 3, l15 = lane & 15;
  const int st_t = tid >> 4;            // staging row 0..31
  const int st_c = (tid & 15) << 4;     // staging col base
  const int i_r = tid & 255;            // recurrence row
  const int h2  = tid >> 8;

  f4v sw[4];                            // staged w (next-next tile)

  for (int bi = 0; bi < NBATCH; ++bi) {
    const int B = blockIdx.x * NBATCH + bi;
    const float* wb = w + (size_t)B * 65536;
    const int Bn = (B + 1 < 2048) ? (B + 1) : B;
    const float* wbn = w + (size_t)Bn * 65536;

    if (bi == 0) {
      // prologue: tile0 -> wt[0]; stage tile1 into regs
      const float* src0 = wb + st_t * 256 + st_c;
#pragma unroll
      for (int q = 0; q < 4; ++q) sw[q] = *(const f4v*)(src0 + q * 4);
      {
        _Float16* dst = (_Float16*)(smem + WT0_OFF) + st_t * WT_STRIDE + st_c;
        *(h8v*)dst = cvt8(sw[0], sw[1]);
        *(h8v*)(dst + 8) = cvt8(sw[2], sw[3]);
      }
      const float* src1 = wb + (32 + st_t) * 256 + st_c;
#pragma unroll
      for (int q = 0; q < 4; ++q) sw[q] = *(const f4v*)(src1 + q * 4);
      BAR();
    }

    f4v acc2[2][16];
#pragma unroll
    for (int jt = 0; jt < 2; ++jt)
#pragma unroll
      for (int it = 0; it < 16; ++it) acc2[jt][it] = f4v{0.f, 0.f, 0.f, 0.f};

#pragma unroll 2
    for (int tau = 0; tau < 8; ++tau) {
      // A) write wt[(tau+1)&1] from staged regs (buffer not read this tau)
      {
        _Float16* dst = (_Float16*)(smem + (((tau + 1) & 1) ? WT1_OFF : WT0_OFF))
                        + st_t * WT_STRIDE + st_c;
        *(h8v*)dst = cvt8(sw[0], sw[1]);
        *(h8v*)(dst + 8) = cvt8(sw[2], sw[3]);
      }
      // B) issue w loads for tau+2 (skip past-the-end on last batch)
      {
        const int tld = tau + 2;
        if (bi == 0 || tld <= 7) {
          const float* src = (tld <= 7)
              ? (wb  + (size_t)(tld * 32 + st_t) * 256 + st_c)
              : (wbn + (size_t)((tld - 8) * 32 + st_t) * 256 + st_c);
#pragma unroll
          for (int q = 0; q < 4; ++q) sw[q] = *(const f4v*)(src + q * 4);
        }
      }
      // C) GEMM1(tau): T fragments (A = wt[cur], B = wvp from L2)
      f4v acc1[2][2];
#pragma unroll
      for (int a = 0; a < 2; ++a)
#pragma unroll
        for (int b2 = 0; b2 < 2; ++b2) acc1[a][b2] = f4v{0.f, 0.f, 0.f, 0.f};
      {
        const _Float16* wt = (const _Float16*)(smem + ((tau & 1) ? WT1_OFF : WT0_OFF));
#pragma unroll
        for (int kk = 0; kk < 8; ++kk) {
          h8v a0, a1;
          LDH(wt + (l15) * WT_STRIDE, kk, a0);
          LDH(wt + (16 + l15) * WT_STRIDE, kk, a1);
#pragma unroll
          for (int jn = 0; jn < 2; ++jn) {
            const int JN = wv * 2 + jn;
            h8v bf = *(const h8v*)(wvp + ((size_t)(JN * 8 + kk) * 64 + lane) * 8);
            acc1[0][jn] = mfma16(a0, bf, acc1[0][jn]);
            acc1[1][jn] = mfma16(a1, bf, acc1[1][jn]);
          }
        }
      }
      // D) write Tt(tau) — wave-local rows, no barrier needed before E
#pragma unroll
      for (int tm = 0; tm < 2; ++tm)
#pragma unroll
        for (int jn = 0; jn < 2; ++jn) {
          const int j = wv * 32 + jn * 16 + l15;
          f4v a = acc1[tm][jn];
          h4v t4; t4[0] = (_Float16)a[0]; t4[1] = (_Float16)a[1];
          t4[2] = (_Float16)a[2]; t4[3] = (_Float16)a[3];
          *(h4v*)(TT + j * TT_STRIDE + tm * 16 + g * 4) = t4;
        }
      // E) GEMM2(tau): G += Tt * Ww  (A = TT wave-local, B = wwp2 from L2)
      {
        h8v a0, a1;
        LDH(TT + (wv * 32 + l15) * TT_STRIDE, 0, a0);
        LDH(TT + (wv * 32 + 16 + l15) * TT_STRIDE, 0, a1);
        const _Float16* wws = wwp2 + (size_t)tau * 8192;
#pragma unroll
        for (int it = 0; it < 16; ++it) {
          h8v bf = *(const h8v*)(wws + ((size_t)(it * 64 + lane)) * 8);
          acc2[0][it] = mfma16(a0, bf, acc2[0][it]);
          acc2[1][it] = mfma16(a1, bf, acc2[1][it]);
        }
      }
      // F) one barrier per tau (orders wt[next] writes vs next-tau reads)
      BAR();
    } // tau

    // ---- G bounce: 8 chunks of 32 i-rows through TT region ----
    uint4 gq[16];
    _Float16* const GC = TT;   // stride GC_STRIDE halves
#pragma unroll
    for (int c = 0; c < 8; ++c) {
#pragma unroll
      for (int jt = 0; jt < 2; ++jt)
#pragma unroll
        for (int e = 0; e < 2; ++e) {
          const int IT = 2 * c + e;
          const int il = e * 16 + l15;                 // i - c*32
          const int j  = wv * 32 + jt * 16 + g * 4;
          f4v a = acc2[jt][IT];
          h4v t4; t4[0] = (_Float16)a[0]; t4[1] = (_Float16)a[1];
          t4[2] = (_Float16)a[2]; t4[3] = (_Float16)a[3];
          *(h4v*)(GC + il * GC_STRIDE + j) = t4;       // row il, cols j..j+3
        }
      BAR();
      if ((i_r >> 5) == c) {
        const int il = i_r & 31;
        const char* row = (const char*)(GC + il * GC_STRIDE) + h2 * 256;
#pragma unroll
        for (int q = 0; q < 16; ++q) {
          u64 lo = *(const u64*)(row + q * 16);
          u64 hi = *(const u64*)(row + q * 16 + 8);
          uint4 v;
          ((u64*)&v)[0] = lo; ((u64*)&v)[1] = hi;
          gq[q] = v;
        }
      }
      BAR();
    }

    // ---- recurrence (proven structure) ----
    uint4 wq[16];
    {
      const uint4* wrow = (const uint4*)(wup + (size_t)i_r * WUP_STRIDE) + h2 * 16;
#pragma unroll
      for (int q = 0; q < 16; ++q) wq[q] = wrow[q];
    }
    float my_beta = beta[(size_t)B * 256 + i_r];

    if (tid < 256) HS[tid] = (_Float16)0.f; else CS[tid - 256] = (_Float16)0.f;
    float cm = 0.f;
    BAR();

    const uint4* hrow = (const uint4*)((const char*)HS + h2 * 256);
    const uint4* crow = (const uint4*)((const char*)CS + h2 * 256);

    for (int t = 0; t < 20; ++t) {
      float au[4] = {0.f, 0.f, 0.f, 0.f};
      float ag[4] = {0.f, 0.f, 0.f, 0.f};
#pragma unroll
      for (int q = 0; q < 16; ++q) {
        uint4 wu4 = wq[q];
        uint4 gg  = gq[q];
        uint4 hv  = hrow[q];
        uint4 cv  = crow[q];
        float a = au[q & 3], e = ag[q & 3];
        a = dot2f(wu4.x, hv.x, a);
        a = dot2f(wu4.y, hv.y, a);
        a = dot2f(wu4.z, hv.z, a);
        a = dot2f(wu4.w, hv.w, a);
        e = dot2f(gg.x, cv.x, e);
        e = dot2f(gg.y, cv.y, e);
        e = dot2f(gg.z, cv.z, e);
        e = dot2f(gg.w, cv.w, e);
        au[q & 3] = a; ag[q & 3] = e;
      }
      float auf = (au[0] + au[1]) + (au[2] + au[3]);
      float agf = (ag[0] + ag[1]) + (ag[2] + ag[3]);
      P[tid] = (auf - agf) * 128.f;   // descale 2^7
      BAR();
      float y = my_beta + P[i_r] + P[i_r + 256];
      float hval = fmaxf(y, 0.f);
      if (h2 == 0) {
        cm += hval;
        HS[i_r] = (_Float16)(hval * 0.0078125f);  // * 2^-7
        CS[i_r] = (_Float16)(cm * 0.0078125f);
      }
      BAR();
    }
    if (h2 == 0) cout[(size_t)B * 256 + i_r] = cm;
    BAR();   // protect LDS before next batch
  } // bi
}

extern "C" void kernel_launch(void* const* d_in, const int* in_sizes, int n_in,
                              void* d_out, int out_size, void* d_ws, size_t ws_size,
                              hipStream_t stream)
{
  const float* w  = (const float*)d_in[0];
  const float* b  = (const float*)d_in[1];
  const float* Ww = (const float*)d_in[2];
  const float* Wu = (const float*)d_in[3];
  const float* Wv = (const float*)d_in[4];

  char* ws = (char*)d_ws;
  float*    beta = (float*)(ws);
  float*    cbuf = (float*)(ws + (size_t)2 * 1024 * 1024);
  _Float16* wvp  = (_Float16*)(ws + (size_t)4 * 1024 * 1024);
  _Float16* wwp2 = (_Float16*)(ws + (size_t)4 * 1024 * 1024 + 131072);
  _Float16* wup  = (_Float16*)(ws + (size_t)4 * 1024 * 1024 + 262144);

  (void)in_sizes; (void)n_in; (void)out_size; (void)ws_size;

  hipFuncSetAttribute((const void*)fused_k,
                      hipFuncAttributeMaxDynamicSharedMemorySize, LDS_FUSED);

  prep_k<<<256, 256, 0, stream>>>(Wu, wup);
  prep2_k<<<256, 256, 0, stream>>>(Wv, Ww, wvp, wwp2);
  matvec_k<<<2048, 256, 0, stream>>>(Ww, b, beta);                  // beta = Ww @ b
  fused_k<<<1024, 512, LDS_FUSED, stream>>>(w, wvp, wwp2, wup, beta, cbuf);
  matvec_k<<<2048, 256, 0, stream>>>(Wv, cbuf, (float*)d_out);      // x = Wv @ c
}

// Round 11
// 702.207 us; speedup vs baseline: 2.7659x; 1.2289x over previous
//
#include <hip/hip_runtime.h>

typedef _Float16 h2v __attribute__((ext_vector_type(2)));
typedef _Float16 h4v __attribute__((ext_vector_type(4)));
typedef _Float16 h8v __attribute__((ext_vector_type(8)));
typedef float    f4v __attribute__((ext_vector_type(4)));
typedef unsigned int u32;
typedef unsigned long long u64;

#define WUP_STRIDE 264        // wup padded row (halves)

// LDS layout (bytes) for fused_k (1024 threads, total 57344)
#define WT_STRIDE 264         // halves per w-tile row (528 B)
#define WT0_OFF   0
#define WT1_OFF   16896       // 32*264*2
#define TT_OFF    33792       // 256 rows * 36 halves * 2 = 18432
#define TT_STRIDE 36          // halves per Tt row (72 B)
#define GC_STRIDE 268         // halves per G-chunk row; 32*536=17152 <= 18432
#define P_OFF     52224       // 1024 f32 = 4096
#define HS_OFF    56320
#define CS_OFF    56832
#define LDS_FUSED 57344

__device__ inline f4v mfma16(h8v a, h8v b, f4v c) {
  return __builtin_amdgcn_mfma_f32_16x16x32_f16(a, b, c, 0, 0, 0);
}

__device__ inline float dot2f(u32 a, u32 b, float c) {
#if __has_builtin(__builtin_amdgcn_fdot2)
  return __builtin_amdgcn_fdot2(__builtin_bit_cast(h2v, a), __builtin_bit_cast(h2v, b), c, false);
#else
  h2v av = __builtin_bit_cast(h2v, a), bv = __builtin_bit_cast(h2v, b);
  return c + (float)av[0] * (float)bv[0] + (float)av[1] * (float)bv[1];
#endif
}

__device__ inline h8v cvt8(f4v lo, f4v hi) {
  h8v d;
  d[0] = (_Float16)lo[0]; d[1] = (_Float16)lo[1]; d[2] = (_Float16)lo[2]; d[3] = (_Float16)lo[3];
  d[4] = (_Float16)hi[0]; d[5] = (_Float16)hi[1]; d[6] = (_Float16)hi[2]; d[7] = (_Float16)hi[3];
  return d;
}

// raw barrier: LDS-visibility only, never drains vmcnt
#define BAR() { asm volatile("s_waitcnt lgkmcnt(0)" ::: "memory"); \
                __builtin_amdgcn_s_barrier(); \
                asm volatile("" ::: "memory"); }

// fragment loader: ROW-BASE pointer; kk/g offsets applied exactly once
#define LDH(basep, kk, dst) { \
    h4v lo_ = *(const h4v*)((basep) + (kk)*32 + 4*g); \
    h4v hi_ = *(const h4v*)((basep) + (kk)*32 + 16 + 4*g); \
    dst = __builtin_shufflevector(lo_, hi_, 0, 1, 2, 3, 4, 5, 6, 7); }

// ---- prep: Wu padded row-major (for recurrence row pulls) ----
__global__ void prep_k(const float* __restrict__ Wu, _Float16* __restrict__ wup)
{
  int j = blockIdx.x, k = threadIdx.x;
  wup[j * WUP_STRIDE + k] = (_Float16)Wu[j * 256 + k];
  if (k < 8) wup[j * WUP_STRIDE + 256 + k] = (_Float16)0.f;
}

// ---- prep2: pack Wv (wvp) and Ww (wwp2, t-sliced) into MFMA B-frag order ----
// koff(g,h) = h<4 ? 4g+h : 16+4g+(h-4)
// wvp [(nt*8+kk)*64+lane]*8+h  = Wv[kk*32+koff][nt*16+l15]
// wwp2[(tau*16+it)*64+lane]*8+h = Ww[it*16+l15][tau*32+koff]
__global__ void prep2_k(const float* __restrict__ Wv, const float* __restrict__ Ww,
                        _Float16* __restrict__ wvp, _Float16* __restrict__ wwp2)
{
  int b = blockIdx.x;
  int tid = threadIdx.x;
  int lane = tid & 63, q = tid >> 6;
  int g2 = (lane >> 4) & 3, l15 = lane & 15;
  if (b < 128) {
    int nt = b >> 3, kk = b & 7;
    int j = nt * 16 + l15;
    _Float16* dst = wvp + ((size_t)(b * 64 + lane)) * 8;
#pragma unroll
    for (int e = 0; e < 2; ++e) {
      int h = 2 * q + e;
      int k = kk * 32 + (h < 4 ? 4 * g2 + h : 16 + 4 * g2 + (h - 4));
      dst[h] = (_Float16)Wv[(size_t)k * 256 + j];
    }
  } else {
    int s = b - 128;                 // tau*16 + it
    int it = s & 15;
    int tau = s >> 4;
    int i = it * 16 + l15;
    _Float16* dst = wwp2 + ((size_t)(s * 64 + lane)) * 8;
#pragma unroll
    for (int e = 0; e < 2; ++e) {
      int h = 2 * q + e;
      int t = tau * 32 + (h < 4 ? 4 * g2 + h : 16 + 4 * g2 + (h - 4));
      dst[h] = (_Float16)Ww[(size_t)i * 256 + t];
    }
  }
}

// out[b,i] = sum_j M[i,j] * V[b,j]   (beta = Ww@b ; final x = Wv@c)
__global__ void matvec_k(const float* __restrict__ M, const float* __restrict__ V,
                         float* __restrict__ out)
{
  __shared__ float vb[256];
  int b = blockIdx.x, i = threadIdx.x;
  vb[i] = V[(size_t)b * 256 + i];
  __syncthreads();
  float a0 = 0.f;
#pragma unroll 8
  for (int j = 0; j < 256; j += 4) {
    f4v m = *(const f4v*)(M + (size_t)i * 256 + j);
    a0 += m[0] * vb[j] + m[1] * vb[j + 1] + m[2] * vb[j + 2] + m[3] * vb[j + 3];
  }
  out[(size_t)b * 256 + i] = a0;
}

// ================= fused (1024 thr, 16 waves, 1 batch/block) ================
// tau = 0..7 (32 t-rows each), ONE barrier per tau:
//   write wt[next] from staged regs; issue w loads for tau+2;
//   GEMM1: T[tau] = w_tile @ Wv   (wave wv owns j-cols [wv*16,wv*16+16))
//   GEMM2: G += Ww[:,tau] @ T[tau] (wave wv owns j-rows, 16 i-frags) -> acc2[16]
// Then G-bounce (8 chunks) + 20-step recurrence (4-way split per row).
// acc2 = 64 f32/thread -> total regs ~110 -> 16 waves resident (the round-10
// 512-thr shape needed 128 acc regs -> 256 total -> stuck at 8 waves/CU).
__global__ __launch_bounds__(1024, 1) void fused_k(
    const float* __restrict__ w, const _Float16* __restrict__ wvp,
    const _Float16* __restrict__ wwp2, const _Float16* __restrict__ wup,
    const float* __restrict__ beta, float* __restrict__ cout)
{
  extern __shared__ char smem[];
  _Float16* const TT = (_Float16*)(smem + TT_OFF);
  float*    const P  = (float*)(smem + P_OFF);
  _Float16* const HS = (_Float16*)(smem + HS_OFF);
  _Float16* const CS = (_Float16*)(smem + CS_OFF);

  const int tid = threadIdx.x;
  const int wv = tid >> 6, lane = tid & 63;
  const int g = (lane >> 4) & 3, l15 = lane & 15;
  const int st_t = tid >> 5;            // staging row 0..31
  const int st_c = (tid & 31) * 8;      // staging col base (floats)
  const int i_r = tid & 255;            // recurrence row
  const int qh  = tid >> 8;             // quarter 0..3 (j-range qh*64..+64)
  const int B   = blockIdx.x;
  const float* wb = w + (size_t)B * 65536;

  f4v sw[2];                            // staged w (next-next tile), 32B/thread

  // prologue: tile0 -> wt[0]; stage tile1 into regs
  {
    const float* src0 = wb + (size_t)st_t * 256 + st_c;
    sw[0] = *(const f4v*)(src0);
    sw[1] = *(const f4v*)(src0 + 4);
    _Float16* dst = (_Float16*)(smem + WT0_OFF) + st_t * WT_STRIDE + st_c;
    *(h8v*)dst = cvt8(sw[0], sw[1]);
    const float* src1 = wb + (size_t)(32 + st_t) * 256 + st_c;
    sw[0] = *(const f4v*)(src1);
    sw[1] = *(const f4v*)(src1 + 4);
    BAR();
  }

  f4v acc2[16];
#pragma unroll
  for (int it = 0; it < 16; ++it) acc2[it] = f4v{0.f, 0.f, 0.f, 0.f};

#pragma unroll 2
  for (int tau = 0; tau < 8; ++tau) {
    // A) write wt[(tau+1)&1] from staged regs
    if (tau < 7) {
      _Float16* dst = (_Float16*)(smem + (((tau + 1) & 1) ? WT1_OFF : WT0_OFF))
                      + st_t * WT_STRIDE + st_c;
      *(h8v*)dst = cvt8(sw[0], sw[1]);
    }
    // B) issue w loads for tau+2
    if (tau < 6) {
      const float* src = wb + (size_t)((tau + 2) * 32 + st_t) * 256 + st_c;
      sw[0] = *(const f4v*)(src);
      sw[1] = *(const f4v*)(src + 4);
    }
    // C) GEMM1(tau): wave wv covers j = wv*16..wv*16+15 (nt = wv)
    f4v acc1[2];
    acc1[0] = f4v{0.f, 0.f, 0.f, 0.f};
    acc1[1] = f4v{0.f, 0.f, 0.f, 0.f};
    {
      const _Float16* wt = (const _Float16*)(smem + ((tau & 1) ? WT1_OFF : WT0_OFF));
#pragma unroll
      for (int kk = 0; kk < 8; ++kk) {
        h8v a0, a1;
        LDH(wt + (l15) * WT_STRIDE, kk, a0);            // t rows 0..15
        LDH(wt + (16 + l15) * WT_STRIDE, kk, a1);       // t rows 16..31
        h8v bf = *(const h8v*)(wvp + ((size_t)((wv * 8 + kk) * 64 + lane)) * 8);
        acc1[0] = mfma16(a0, bf, acc1[0]);
        acc1[1] = mfma16(a1, bf, acc1[1]);
      }
    }
    // D) write Tt(tau): rows j = wv*16+l15 (wave-local), cols t
#pragma unroll
    for (int tm = 0; tm < 2; ++tm) {
      const int j = wv * 16 + l15;
      f4v a = acc1[tm];
      h4v t4; t4[0] = (_Float16)a[0]; t4[1] = (_Float16)a[1];
      t4[2] = (_Float16)a[2]; t4[3] = (_Float16)a[3];
      *(h4v*)(TT + j * TT_STRIDE + tm * 16 + g * 4) = t4;
    }
    // E) GEMM2(tau): acc2[it] += Tt(j-rows, t) * Ww(i, t)
    {
      h8v a0;
      LDH(TT + (wv * 16 + l15) * TT_STRIDE, 0, a0);     // wave-local rows
      const _Float16* wws = wwp2 + (size_t)tau * 8192;
#pragma unroll
      for (int it = 0; it < 16; ++it) {
        h8v bf = *(const h8v*)(wws + ((size_t)(it * 64 + lane)) * 8);
        acc2[it] = mfma16(a0, bf, acc2[it]);
      }
    }
    // F) one barrier per tau
    BAR();
  } // tau

  // ---- G bounce: 8 chunks of 32 i-rows through TT region ----
  // lane holds acc2[it] = G[j = wv*16 + g*4 + r][i = it*16 + l15]
  uint4 gq[8];
  _Float16* const GC = TT;
#pragma unroll
  for (int c = 0; c < 8; ++c) {
#pragma unroll
    for (int e = 0; e < 2; ++e) {
      const int IT = 2 * c + e;
      const int il = e * 16 + l15;                 // i - c*32
      const int j  = wv * 16 + g * 4;
      f4v a = acc2[IT];
      h4v t4; t4[0] = (_Float16)a[0]; t4[1] = (_Float16)a[1];
      t4[2] = (_Float16)a[2]; t4[3] = (_Float16)a[3];
      *(h4v*)(GC + il * GC_STRIDE + j) = t4;
    }
    BAR();
    if ((i_r >> 5) == c) {
      const char* row = (const char*)(GC + (i_r & 31) * GC_STRIDE) + qh * 128;
#pragma unroll
      for (int q = 0; q < 8; ++q)
        gq[q] = *(const uint4*)(row + q * 16);
    }
    BAR();
  }

  // ---- recurrence: thread (i_r, qh) owns j-range [qh*64, qh*64+64) ----
  uint4 wq[8];
  {
    const uint4* wrow = (const uint4*)(wup + (size_t)i_r * WUP_STRIDE) + qh * 8;
#pragma unroll
    for (int q = 0; q < 8; ++q) wq[q] = wrow[q];
  }
  float my_beta = beta[(size_t)B * 256 + i_r];

  if (tid < 256) HS[tid] = (_Float16)0.f;
  else if (tid < 512) CS[tid - 256] = (_Float16)0.f;
  float cm = 0.f;
  BAR();

  const uint4* hrow = (const uint4*)((const char*)HS + qh * 128);
  const uint4* crow = (const uint4*)((const char*)CS + qh * 128);

  for (int t = 0; t < 20; ++t) {
    float au[4] = {0.f, 0.f, 0.f, 0.f};
    float ag[4] = {0.f, 0.f, 0.f, 0.f};
#pragma unroll
    for (int q = 0; q < 8; ++q) {
      uint4 wu4 = wq[q];
      uint4 gg  = gq[q];
      uint4 hv  = hrow[q];
      uint4 cv  = crow[q];
      float a = au[q & 3], e = ag[q & 3];
      a = dot2f(wu4.x, hv.x, a);
      a = dot2f(wu4.y, hv.y, a);
      a = dot2f(wu4.z, hv.z, a);
      a = dot2f(wu4.w, hv.w, a);
      e = dot2f(gg.x, cv.x, e);
      e = dot2f(gg.y, cv.y, e);
      e = dot2f(gg.z, cv.z, e);
      e = dot2f(gg.w, cv.w, e);
      au[q & 3] = a; ag[q & 3] = e;
    }
    float auf = (au[0] + au[1]) + (au[2] + au[3]);
    float agf = (ag[0] + ag[1]) + (ag[2] + ag[3]);
    P[tid] = (auf - agf) * 128.f;   // descale 2^7
    BAR();
    float y = my_beta + P[i_r] + P[i_r + 256] + P[i_r + 512] + P[i_r + 768];
    float hval = fmaxf(y, 0.f);
    if (qh == 0) {
      cm += hval;
      HS[i_r] = (_Float16)(hval * 0.0078125f);  // * 2^-7
      CS[i_r] = (_Float16)(cm * 0.0078125f);
    }
    BAR();
  }
  if (qh == 0) cout[(size_t)B * 256 + i_r] = cm;
}

extern "C" void kernel_launch(void* const* d_in, const int* in_sizes, int n_in,
                              void* d_out, int out_size, void* d_ws, size_t ws_size,
                              hipStream_t stream)
{
  const float* w  = (const float*)d_in[0];
  const float* b  = (const float*)d_in[1];
  const float* Ww = (const float*)d_in[2];
  const float* Wu = (const float*)d_in[3];
  const float* Wv = (const float*)d_in[4];

  char* ws = (char*)d_ws;
  float*    beta = (float*)(ws);
  float*    cbuf = (float*)(ws + (size_t)2 * 1024 * 1024);
  _Float16* wvp  = (_Float16*)(ws + (size_t)4 * 1024 * 1024);
  _Float16* wwp2 = (_Float16*)(ws + (size_t)4 * 1024 * 1024 + 131072);
  _Float16* wup  = (_Float16*)(ws + (size_t)4 * 1024 * 1024 + 262144);

  (void)in_sizes; (void)n_in; (void)out_size; (void)ws_size;

  hipFuncSetAttribute((const void*)fused_k,
                      hipFuncAttributeMaxDynamicSharedMemorySize, LDS_FUSED);

  prep_k<<<256, 256, 0, stream>>>(Wu, wup);
  prep2_k<<<256, 256, 0, stream>>>(Wv, Ww, wvp, wwp2);
  matvec_k<<<2048, 256, 0, stream>>>(Ww, b, beta);                  // beta = Ww @ b
  fused_k<<<2048, 1024, LDS_FUSED, stream>>>(w, wvp, wwp2, wup, beta, cbuf);
  matvec_k<<<2048, 256, 0, stream>>>(Wv, cbuf, (float*)d_out);      // x = Wv @ c
}

// Round 12
// 695.345 us; speedup vs baseline: 2.7932x; 1.0099x over previous
//
#include <hip/hip_runtime.h>

typedef _Float16 h2v __attribute__((ext_vector_type(2)));
typedef _Float16 h4v __attribute__((ext_vector_type(4)));
typedef _Float16 h8v __attribute__((ext_vector_type(8)));
typedef float    f4v __attribute__((ext_vector_type(4)));
typedef unsigned int u32;
typedef unsigned long long u64;

#define WUP_STRIDE 264        // wup padded row (halves)

// LDS layout (bytes) for fused_k (1024 threads)
// GEMM phase: WT0/WT1/TT (52224 B). Then GC (full G) OVERLAYS them.
#define WT_STRIDE 264         // halves per w-tile row (528 B)
#define WT0_OFF   0
#define WT1_OFF   16896       // 32*264*2
#define TT_OFF    33792       // 256 rows * 36 halves * 2 = 18432 -> end 52224
#define TT_STRIDE 36          // halves per Tt row (72 B)
#define GC_OFF    0           // full G 256 x 264 halves = 135168 B (after GEMM)
#define GC_STRIDE 264         // 528 B/row; 528/16=33 odd -> uniform bank-quads
#define P_OFF     135168      // 1024 f32 = 4096
#define HS_OFF    139264
#define CS_OFF    139776
#define LDS_FUSED 140288

__device__ inline f4v mfma16(h8v a, h8v b, f4v c) {
  return __builtin_amdgcn_mfma_f32_16x16x32_f16(a, b, c, 0, 0, 0);
}

__device__ inline float dot2f(u32 a, u32 b, float c) {
#if __has_builtin(__builtin_amdgcn_fdot2)
  return __builtin_amdgcn_fdot2(__builtin_bit_cast(h2v, a), __builtin_bit_cast(h2v, b), c, false);
#else
  h2v av = __builtin_bit_cast(h2v, a), bv = __builtin_bit_cast(h2v, b);
  return c + (float)av[0] * (float)bv[0] + (float)av[1] * (float)bv[1];
#endif
}

__device__ inline h8v cvt8(f4v lo, f4v hi) {
  h8v d;
  d[0] = (_Float16)lo[0]; d[1] = (_Float16)lo[1]; d[2] = (_Float16)lo[2]; d[3] = (_Float16)lo[3];
  d[4] = (_Float16)hi[0]; d[5] = (_Float16)hi[1]; d[6] = (_Float16)hi[2]; d[7] = (_Float16)hi[3];
  return d;
}

// raw barrier: LDS-visibility only, never drains vmcnt
#define BAR() { asm volatile("s_waitcnt lgkmcnt(0)" ::: "memory"); \
                __builtin_amdgcn_s_barrier(); \
                asm volatile("" ::: "memory"); }

// fragment loader: ROW-BASE pointer; kk/g offsets applied exactly once
#define LDH(basep, kk, dst) { \
    h4v lo_ = *(const h4v*)((basep) + (kk)*32 + 4*g); \
    h4v hi_ = *(const h4v*)((basep) + (kk)*32 + 16 + 4*g); \
    dst = __builtin_shufflevector(lo_, hi_, 0, 1, 2, 3, 4, 5, 6, 7); }

// ---- prep: Wu padded row-major (for recurrence row pulls) ----
__global__ void prep_k(const float* __restrict__ Wu, _Float16* __restrict__ wup)
{
  int j = blockIdx.x, k = threadIdx.x;
  wup[j * WUP_STRIDE + k] = (_Float16)Wu[j * 256 + k];
  if (k < 8) wup[j * WUP_STRIDE + 256 + k] = (_Float16)0.f;
}

// ---- prep2: pack Wv (wvp) and Ww (wwp2, t-sliced) into MFMA B-frag order ----
// koff(g,h) = h<4 ? 4g+h : 16+4g+(h-4)
// wvp [(nt*8+kk)*64+lane]*8+h  = Wv[kk*32+koff][nt*16+l15]
// wwp2[(tau*16+it)*64+lane]*8+h = Ww[it*16+l15][tau*32+koff]
__global__ void prep2_k(const float* __restrict__ Wv, const float* __restrict__ Ww,
                        _Float16* __restrict__ wvp, _Float16* __restrict__ wwp2)
{
  int b = blockIdx.x;
  int tid = threadIdx.x;
  int lane = tid & 63, q = tid >> 6;
  int g2 = (lane >> 4) & 3, l15 = lane & 15;
  if (b < 128) {
    int nt = b >> 3, kk = b & 7;
    int j = nt * 16 + l15;
    _Float16* dst = wvp + ((size_t)(b * 64 + lane)) * 8;
#pragma unroll
    for (int e = 0; e < 2; ++e) {
      int h = 2 * q + e;
      int k = kk * 32 + (h < 4 ? 4 * g2 + h : 16 + 4 * g2 + (h - 4));
      dst[h] = (_Float16)Wv[(size_t)k * 256 + j];
    }
  } else {
    int s = b - 128;                 // tau*16 + it
    int it = s & 15;
    int tau = s >> 4;
    int i = it * 16 + l15;
    _Float16* dst = wwp2 + ((size_t)(s * 64 + lane)) * 8;
#pragma unroll
    for (int e = 0; e < 2; ++e) {
      int h = 2 * q + e;
      int t = tau * 32 + (h < 4 ? 4 * g2 + h : 16 + 4 * g2 + (h - 4));
      dst[h] = (_Float16)Ww[(size_t)i * 256 + t];
    }
  }
}

// out[b,i] = sum_j M[i,j] * V[b,j]   (beta = Ww@b ; final x = Wv@c)
__global__ void matvec_k(const float* __restrict__ M, const float* __restrict__ V,
                         float* __restrict__ out)
{
  __shared__ float vb[256];
  int b = blockIdx.x, i = threadIdx.x;
  vb[i] = V[(size_t)b * 256 + i];
  __syncthreads();
  float a0 = 0.f;
#pragma unroll 8
  for (int j = 0; j < 256; j += 4) {
    f4v m = *(const f4v*)(M + (size_t)i * 256 + j);
    a0 += m[0] * vb[j] + m[1] * vb[j + 1] + m[2] * vb[j + 2] + m[3] * vb[j + 3];
  }
  out[(size_t)b * 256 + i] = a0;
}

// ================= fused (1024 thr, 16 waves, 1 batch/block) ================
// GEMM phase identical to round 11. Then: full G -> LDS (one write + one
// barrier), recurrence reads its G row-quarter from LDS each step (8x b128 at
// floor rate), Wu quarter stays in 32 regs. No gq register residency -> no
// hot-loop spills (round-11 failure mode: VGPR_Count=64 with 64 regs of live
// matrix data -> per-iteration scratch/L2 reloads).
__global__ __launch_bounds__(1024, 1) void fused_k(
    const float* __restrict__ w, const _Float16* __restrict__ wvp,
    const _Float16* __restrict__ wwp2, const _Float16* __restrict__ wup,
    const float* __restrict__ beta, float* __restrict__ cout)
{
  extern __shared__ char smem[];
  _Float16* const TT = (_Float16*)(smem + TT_OFF);
  float*    const P  = (float*)(smem + P_OFF);
  _Float16* const HS = (_Float16*)(smem + HS_OFF);
  _Float16* const CS = (_Float16*)(smem + CS_OFF);

  const int tid = threadIdx.x;
  const int wv = tid >> 6, lane = tid & 63;
  const int g = (lane >> 4) & 3, l15 = lane & 15;
  const int st_t = tid >> 5;            // staging row 0..31
  const int st_c = (tid & 31) * 8;      // staging col base (floats)
  const int i_r = tid & 255;            // recurrence row
  const int qh  = tid >> 8;             // quarter 0..3 (j-range qh*64..+64)
  const int B   = blockIdx.x;
  const float* wb = w + (size_t)B * 65536;

  f4v sw[2];                            // staged w (next-next tile), 32B/thread

  // prologue: tile0 -> wt[0]; stage tile1 into regs
  {
    const float* src0 = wb + (size_t)st_t * 256 + st_c;
    sw[0] = *(const f4v*)(src0);
    sw[1] = *(const f4v*)(src0 + 4);
    _Float16* dst = (_Float16*)(smem + WT0_OFF) + st_t * WT_STRIDE + st_c;
    *(h8v*)dst = cvt8(sw[0], sw[1]);
    const float* src1 = wb + (size_t)(32 + st_t) * 256 + st_c;
    sw[0] = *(const f4v*)(src1);
    sw[1] = *(const f4v*)(src1 + 4);
    BAR();
  }

  f4v acc2[16];
#pragma unroll
  for (int it = 0; it < 16; ++it) acc2[it] = f4v{0.f, 0.f, 0.f, 0.f};

#pragma unroll 2
  for (int tau = 0; tau < 8; ++tau) {
    // A) write wt[(tau+1)&1] from staged regs
    if (tau < 7) {
      _Float16* dst = (_Float16*)(smem + (((tau + 1) & 1) ? WT1_OFF : WT0_OFF))
                      + st_t * WT_STRIDE + st_c;
      *(h8v*)dst = cvt8(sw[0], sw[1]);
    }
    // B) issue w loads for tau+2
    if (tau < 6) {
      const float* src = wb + (size_t)((tau + 2) * 32 + st_t) * 256 + st_c;
      sw[0] = *(const f4v*)(src);
      sw[1] = *(const f4v*)(src + 4);
    }
    // C) GEMM1(tau): wave wv covers j = wv*16..wv*16+15 (nt = wv)
    f4v acc1[2];
    acc1[0] = f4v{0.f, 0.f, 0.f, 0.f};
    acc1[1] = f4v{0.f, 0.f, 0.f, 0.f};
    {
      const _Float16* wt = (const _Float16*)(smem + ((tau & 1) ? WT1_OFF : WT0_OFF));
#pragma unroll
      for (int kk = 0; kk < 8; ++kk) {
        h8v a0, a1;
        LDH(wt + (l15) * WT_STRIDE, kk, a0);            // t rows 0..15
        LDH(wt + (16 + l15) * WT_STRIDE, kk, a1);       // t rows 16..31
        h8v bf = *(const h8v*)(wvp + ((size_t)((wv * 8 + kk) * 64 + lane)) * 8);
        acc1[0] = mfma16(a0, bf, acc1[0]);
        acc1[1] = mfma16(a1, bf, acc1[1]);
      }
    }
    // D) write Tt(tau): rows j = wv*16+l15 (wave-local), cols t
#pragma unroll
    for (int tm = 0; tm < 2; ++tm) {
      const int j = wv * 16 + l15;
      f4v a = acc1[tm];
      h4v t4; t4[0] = (_Float16)a[0]; t4[1] = (_Float16)a[1];
      t4[2] = (_Float16)a[2]; t4[3] = (_Float16)a[3];
      *(h4v*)(TT + j * TT_STRIDE + tm * 16 + g * 4) = t4;
    }
    // E) GEMM2(tau): acc2[it] += Tt(j-rows, t) * Ww(i, t)
    {
      h8v a0;
      LDH(TT + (wv * 16 + l15) * TT_STRIDE, 0, a0);     // wave-local rows
      const _Float16* wws = wwp2 + (size_t)tau * 8192;
#pragma unroll
      for (int it = 0; it < 16; ++it) {
        h8v bf = *(const h8v*)(wws + ((size_t)(it * 64 + lane)) * 8);
        acc2[it] = mfma16(a0, bf, acc2[it]);
      }
    }
    // F) one barrier per tau
    BAR();
  } // tau

  // ---- write FULL G into LDS (overlays WT/TT; all GEMM reads done at BAR) --
  // lane holds acc2[it] = G[j = wv*16 + g*4 + reg][i = it*16 + l15]
  // store as GC[i][j] rows (stride 264 halves = 528 B)
  {
    _Float16* const GC = (_Float16*)(smem + GC_OFF);
#pragma unroll
    for (int it = 0; it < 16; ++it) {
      const int i = it * 16 + l15;
      f4v a = acc2[it];
      h4v t4; t4[0] = (_Float16)a[0]; t4[1] = (_Float16)a[1];
      t4[2] = (_Float16)a[2]; t4[3] = (_Float16)a[3];
      *(h4v*)(GC + (size_t)i * GC_STRIDE + wv * 16 + g * 4) = t4;
    }
  }

  // ---- Wu quarter -> 32 regs (pin so it is not rematerialized per step) ----
  uint4 wq[8];
  {
    const uint4* wrow = (const uint4*)(wup + (size_t)i_r * WUP_STRIDE) + qh * 8;
#pragma unroll
    for (int q = 0; q < 8; ++q) wq[q] = wrow[q];
#pragma unroll
    for (int q = 0; q < 8; ++q)
      asm volatile("" : "+v"(wq[q].x), "+v"(wq[q].y), "+v"(wq[q].z), "+v"(wq[q].w));
  }
  float my_beta = beta[(size_t)B * 256 + i_r];

  if (tid < 256) HS[tid] = (_Float16)0.f;
  else if (tid < 512) CS[tid - 256] = (_Float16)0.f;
  float cm = 0.f;
  BAR();   // G visible + HS/CS zeroed

  const uint4* hrow = (const uint4*)((const char*)HS + qh * 128);
  const uint4* crow = (const uint4*)((const char*)CS + qh * 128);
  const char*  gcrow = (const char*)(smem + GC_OFF) + (size_t)i_r * 528 + qh * 128;

  for (int t = 0; t < 20; ++t) {
    uint4 gql[8];
#pragma unroll
    for (int q = 0; q < 8; ++q)
      gql[q] = *(const uint4*)(gcrow + q * 16);
    float au[4] = {0.f, 0.f, 0.f, 0.f};
    float ag[4] = {0.f, 0.f, 0.f, 0.f};
#pragma unroll
    for (int q = 0; q < 8; ++q) {
      uint4 wu4 = wq[q];
      uint4 gg  = gql[q];
      uint4 hv  = hrow[q];
      uint4 cv  = crow[q];
      float a = au[q & 3], e = ag[q & 3];
      a = dot2f(wu4.x, hv.x, a);
      a = dot2f(wu4.y, hv.y, a);
      a = dot2f(wu4.z, hv.z, a);
      a = dot2f(wu4.w, hv.w, a);
      e = dot2f(gg.x, cv.x, e);
      e = dot2f(gg.y, cv.y, e);
      e = dot2f(gg.z, cv.z, e);
      e = dot2f(gg.w, cv.w, e);
      au[q & 3] = a; ag[q & 3] = e;
    }
    float auf = (au[0] + au[1]) + (au[2] + au[3]);
    float agf = (ag[0] + ag[1]) + (ag[2] + ag[3]);
    P[tid] = (auf - agf) * 128.f;   // descale 2^7
    BAR();
    float y = my_beta + P[i_r] + P[i_r + 256] + P[i_r + 512] + P[i_r + 768];
    float hval = fmaxf(y, 0.f);
    if (qh == 0) {
      cm += hval;
      HS[i_r] = (_Float16)(hval * 0.0078125f);  // * 2^-7
      CS[i_r] = (_Float16)(cm * 0.0078125f);
    }
    BAR();
  }
  if (qh == 0) cout[(size_t)B * 256 + i_r] = cm;
}

extern "C" void kernel_launch(void* const* d_in, const int* in_sizes, int n_in,
                              void* d_out, int out_size, void* d_ws, size_t ws_size,
                              hipStream_t stream)
{
  const float* w  = (const float*)d_in[0];
  const float* b  = (const float*)d_in[1];
  const float* Ww = (const float*)d_in[2];
  const float* Wu = (const float*)d_in[3];
  const float* Wv = (const float*)d_in[4];

  char* ws = (char*)d_ws;
  float*    beta = (float*)(ws);
  float*    cbuf = (float*)(ws + (size_t)2 * 1024 * 1024);
  _Float16* wvp  = (_Float16*)(ws + (size_t)4 * 1024 * 1024);
  _Float16* wwp2 = (_Float16*)(ws + (size_t)4 * 1024 * 1024 + 131072);
  _Float16* wup  = (_Float16*)(ws + (size_t)4 * 1024 * 1024 + 262144);

  (void)in_sizes; (void)n_in; (void)out_size; (void)ws_size;

  hipFuncSetAttribute((const void*)fused_k,
                      hipFuncAttributeMaxDynamicSharedMemorySize, LDS_FUSED);

  prep_k<<<256, 256, 0, stream>>>(Wu, wup);
  prep2_k<<<256, 256, 0, stream>>>(Wv, Ww, wvp, wwp2);
  matvec_k<<<2048, 256, 0, stream>>>(Ww, b, beta);                  // beta = Ww @ b
  fused_k<<<2048, 1024, LDS_FUSED, stream>>>(w, wvp, wwp2, wup, beta, cbuf);
  matvec_k<<<2048, 256, 0, stream>>>(Wv, cbuf, (float*)d_out);      // x = Wv @ c
}

// Round 13
// 670.469 us; speedup vs baseline: 2.8968x; 1.0371x over previous
//
#include <hip/hip_runtime.h>

typedef _Float16 h2v __attribute__((ext_vector_type(2)));
typedef _Float16 h4v __attribute__((ext_vector_type(4)));
typedef _Float16 h8v __attribute__((ext_vector_type(8)));
typedef float    f4v __attribute__((ext_vector_type(4)));
typedef unsigned int u32;
typedef unsigned long long u64;

#define WUP_STRIDE 264        // wup padded row (halves)

// LDS layout (bytes) for fused_k (1024 threads)
// GEMM phase: WT0/WT1/TT (52224 B) live inside the GC region (135168 B),
// which is written only after the last tau barrier. VS = step-vector
// double buffer (2 x 2048 B) in B-fragment-swizzled order.
#define WT_STRIDE 264         // halves per w-tile row (528 B)
#define WT0_OFF   0
#define WT1_OFF   16896       // 32*264*2
#define TT_OFF    33792       // 256 rows * 36 halves * 2 = 18432 -> end 52224
#define TT_STRIDE 36          // halves per Tt row (72 B)
#define GC_OFF    0           // full G 256 x 264 halves = 135168 B (after GEMM)
#define GC_STRIDE 264         // 528 B/row
#define VS_OFF    135168      // 2 x 2048 B
#define LDS_FUSED 139264

__device__ inline f4v mfma16(h8v a, h8v b, f4v c) {
  return __builtin_amdgcn_mfma_f32_16x16x32_f16(a, b, c, 0, 0, 0);
}

__device__ inline h8v cvt8(f4v lo, f4v hi) {
  h8v d;
  d[0] = (_Float16)lo[0]; d[1] = (_Float16)lo[1]; d[2] = (_Float16)lo[2]; d[3] = (_Float16)lo[3];
  d[4] = (_Float16)hi[0]; d[5] = (_Float16)hi[1]; d[6] = (_Float16)hi[2]; d[7] = (_Float16)hi[3];
  return d;
}

// raw barrier: LDS-visibility only, never drains vmcnt
#define BAR() { asm volatile("s_waitcnt lgkmcnt(0)" ::: "memory"); \
                __builtin_amdgcn_s_barrier(); \
                asm volatile("" ::: "memory"); }

// fragment loader: ROW-BASE pointer; kk/g offsets applied exactly once
#define LDH(basep, kk, dst) { \
    h4v lo_ = *(const h4v*)((basep) + (kk)*32 + 4*g); \
    h4v hi_ = *(const h4v*)((basep) + (kk)*32 + 16 + 4*g); \
    dst = __builtin_shufflevector(lo_, hi_, 0, 1, 2, 3, 4, 5, 6, 7); }

// ---- prep: Wu padded row-major (A-frag source for the recurrence) ----
__global__ void prep_k(const float* __restrict__ Wu, _Float16* __restrict__ wup)
{
  int j = blockIdx.x, k = threadIdx.x;
  wup[j * WUP_STRIDE + k] = (_Float16)Wu[j * 256 + k];
  if (k < 8) wup[j * WUP_STRIDE + 256 + k] = (_Float16)0.f;
}

// ---- prep2: pack Wv (wvp) and Ww (wwp2, t-sliced) into MFMA B-frag order ----
// koff(g,h) = h<4 ? 4g+h : 16+4g+(h-4)
// wvp [(nt*8+kk)*64+lane]*8+h  = Wv[kk*32+koff][nt*16+l15]
// wwp2[(tau*16+it)*64+lane]*8+h = Ww[it*16+l15][tau*32+koff]
__global__ void prep2_k(const float* __restrict__ Wv, const float* __restrict__ Ww,
                        _Float16* __restrict__ wvp, _Float16* __restrict__ wwp2)
{
  int b = blockIdx.x;
  int tid = threadIdx.x;
  int lane = tid & 63, q = tid >> 6;
  int g2 = (lane >> 4) & 3, l15 = lane & 15;
  if (b < 128) {
    int nt = b >> 3, kk = b & 7;
    int j = nt * 16 + l15;
    _Float16* dst = wvp + ((size_t)(b * 64 + lane)) * 8;
#pragma unroll
    for (int e = 0; e < 2; ++e) {
      int h = 2 * q + e;
      int k = kk * 32 + (h < 4 ? 4 * g2 + h : 16 + 4 * g2 + (h - 4));
      dst[h] = (_Float16)Wv[(size_t)k * 256 + j];
    }
  } else {
    int s = b - 128;                 // tau*16 + it
    int it = s & 15;
    int tau = s >> 4;
    int i = it * 16 + l15;
    _Float16* dst = wwp2 + ((size_t)(s * 64 + lane)) * 8;
#pragma unroll
    for (int e = 0; e < 2; ++e) {
      int h = 2 * q + e;
      int t = tau * 32 + (h < 4 ? 4 * g2 + h : 16 + 4 * g2 + (h - 4));
      dst[h] = (_Float16)Ww[(size_t)i * 256 + t];
    }
  }
}

// out[b,i] = sum_j M[i,j] * V[b,j]   (beta = Ww@b ; final x = Wv@c)
__global__ void matvec_k(const float* __restrict__ M, const float* __restrict__ V,
                         float* __restrict__ out)
{
  __shared__ float vb[256];
  int b = blockIdx.x, i = threadIdx.x;
  vb[i] = V[(size_t)b * 256 + i];
  __syncthreads();
  float a0 = 0.f;
#pragma unroll 8
  for (int j = 0; j < 256; j += 4) {
    f4v m = *(const f4v*)(M + (size_t)i * 256 + j);
    a0 += m[0] * vb[j] + m[1] * vb[j + 1] + m[2] * vb[j + 2] + m[3] * vb[j + 3];
  }
  out[(size_t)b * 256 + i] = a0;
}

// ================= fused (1024 thr, 16 waves, 1 batch/block) ================
// GEMM phase identical to round 12 (proven). Recurrence rebuilt on MFMA:
//   per wave: 16-row i-tile of [Wu | G] held as 16 A-frags (64 VGPR, loaded
//   once: Wu from global, G from the GC LDS bounce). Per step: 16 broadcast
//   ds_read_b128 of the swizzled vector [h*2^-7 ; -c*2^-7] + 16 MFMA; all
//   D-columns are equal (B columns identical), lanes l15==0 run the epilogue
//   and write the next vector. Double-buffered VS -> ONE barrier per step.
__global__ __launch_bounds__(1024, 1) void fused_k(
    const float* __restrict__ w, const _Float16* __restrict__ wvp,
    const _Float16* __restrict__ wwp2, const _Float16* __restrict__ wup,
    const float* __restrict__ beta, float* __restrict__ cout)
{
  extern __shared__ char smem[];
  _Float16* const TT = (_Float16*)(smem + TT_OFF);

  const int tid = threadIdx.x;
  const int wv = tid >> 6, lane = tid & 63;
  const int g = (lane >> 4) & 3, l15 = lane & 15;
  const int st_t = tid >> 5;            // staging row 0..31
  const int st_c = (tid & 31) * 8;      // staging col base (floats)
  const int B   = blockIdx.x;
  const float* wb = w + (size_t)B * 65536;

  f4v sw[2];                            // staged w (next-next tile), 32B/thread

  // prologue: tile0 -> wt[0]; stage tile1 into regs
  {
    const float* src0 = wb + (size_t)st_t * 256 + st_c;
    sw[0] = *(const f4v*)(src0);
    sw[1] = *(const f4v*)(src0 + 4);
    _Float16* dst = (_Float16*)(smem + WT0_OFF) + st_t * WT_STRIDE + st_c;
    *(h8v*)dst = cvt8(sw[0], sw[1]);
    const float* src1 = wb + (size_t)(32 + st_t) * 256 + st_c;
    sw[0] = *(const f4v*)(src1);
    sw[1] = *(const f4v*)(src1 + 4);
    BAR();
  }

  f4v acc2[16];
#pragma unroll
  for (int it = 0; it < 16; ++it) acc2[it] = f4v{0.f, 0.f, 0.f, 0.f};

#pragma unroll 2
  for (int tau = 0; tau < 8; ++tau) {
    // A) write wt[(tau+1)&1] from staged regs
    if (tau < 7) {
      _Float16* dst = (_Float16*)(smem + (((tau + 1) & 1) ? WT1_OFF : WT0_OFF))
                      + st_t * WT_STRIDE + st_c;
      *(h8v*)dst = cvt8(sw[0], sw[1]);
    }
    // B) issue w loads for tau+2
    if (tau < 6) {
      const float* src = wb + (size_t)((tau + 2) * 32 + st_t) * 256 + st_c;
      sw[0] = *(const f4v*)(src);
      sw[1] = *(const f4v*)(src + 4);
    }
    // C) GEMM1(tau): wave wv covers j = wv*16..wv*16+15 (nt = wv)
    f4v acc1[2];
    acc1[0] = f4v{0.f, 0.f, 0.f, 0.f};
    acc1[1] = f4v{0.f, 0.f, 0.f, 0.f};
    {
      const _Float16* wt = (const _Float16*)(smem + ((tau & 1) ? WT1_OFF : WT0_OFF));
#pragma unroll
      for (int kk = 0; kk < 8; ++kk) {
        h8v a0, a1;
        LDH(wt + (l15) * WT_STRIDE, kk, a0);            // t rows 0..15
        LDH(wt + (16 + l15) * WT_STRIDE, kk, a1);       // t rows 16..31
        h8v bf = *(const h8v*)(wvp + ((size_t)((wv * 8 + kk) * 64 + lane)) * 8);
        acc1[0] = mfma16(a0, bf, acc1[0]);
        acc1[1] = mfma16(a1, bf, acc1[1]);
      }
    }
    // D) write Tt(tau): rows j = wv*16+l15 (wave-local), cols t
#pragma unroll
    for (int tm = 0; tm < 2; ++tm) {
      const int j = wv * 16 + l15;
      f4v a = acc1[tm];
      h4v t4; t4[0] = (_Float16)a[0]; t4[1] = (_Float16)a[1];
      t4[2] = (_Float16)a[2]; t4[3] = (_Float16)a[3];
      *(h4v*)(TT + j * TT_STRIDE + tm * 16 + g * 4) = t4;
    }
    // E) GEMM2(tau): acc2[it] += Tt(j-rows, t) * Ww(i, t)
    {
      h8v a0;
      LDH(TT + (wv * 16 + l15) * TT_STRIDE, 0, a0);     // wave-local rows
      const _Float16* wws = wwp2 + (size_t)tau * 8192;
#pragma unroll
      for (int it = 0; it < 16; ++it) {
        h8v bf = *(const h8v*)(wws + ((size_t)(it * 64 + lane)) * 8);
        acc2[it] = mfma16(a0, bf, acc2[it]);
      }
    }
    // F) one barrier per tau
    BAR();
  } // tau

  // ---- write FULL G into LDS (overlays WT/TT; all GEMM reads done at BAR) --
  // lane holds acc2[it] = G[j = wv*16 + g*4 + reg][i = it*16 + l15]
  // store as GC[i][j] rows (stride 264 halves = 528 B)
  {
    _Float16* const GC = (_Float16*)(smem + GC_OFF);
#pragma unroll
    for (int it = 0; it < 16; ++it) {
      const int i = it * 16 + l15;
      f4v a = acc2[it];
      h4v t4; t4[0] = (_Float16)a[0]; t4[1] = (_Float16)a[1];
      t4[2] = (_Float16)a[2]; t4[3] = (_Float16)a[3];
      *(h4v*)(GC + (size_t)i * GC_STRIDE + wv * 16 + g * 4) = t4;
    }
  }
  // zero VS buffer 0 (h=0, c=0)
  if (tid < 256) ((u64*)(smem + VS_OFF))[tid] = 0ull;
  BAR();   // G + VS0 visible

  // ---- load A-frags of [Wu | G] for this wave's 16-row i-tile ----
  h8v af[16];
  {
    const int arow = wv * 16 + l15;
    const _Float16* wurow = wup + (size_t)arow * WUP_STRIDE;
#pragma unroll
    for (int kk = 0; kk < 8; ++kk) { LDH(wurow, kk, af[kk]); }
    const _Float16* gcrow = (const _Float16*)(smem + GC_OFF) + (size_t)arow * GC_STRIDE;
#pragma unroll
    for (int kk = 0; kk < 8; ++kk) { LDH(gcrow, kk, af[8 + kk]); }
  }
  f4v beta4 = *(const f4v*)(beta + (size_t)B * 256 + wv * 16 + 4 * g);
  f4v cm4 = f4v{0.f, 0.f, 0.f, 0.f};

  // producer slot for this (wv,g): u64 index within VS h-part / c-part
  const int vslot = (wv >> 1) * 64 + g * 16 + (wv & 1) * 8;   // byte offset

  for (int t = 0; t < 20; ++t) {
    const char* vsr = smem + VS_OFF + (t & 1) * 2048;
    f4v acc_e = f4v{0.f, 0.f, 0.f, 0.f};
    f4v acc_o = f4v{0.f, 0.f, 0.f, 0.f};
#pragma unroll
    for (int kk = 0; kk < 16; kk += 2) {
      h8v vf0 = *(const h8v*)(vsr + kk * 64 + g * 16);
      h8v vf1 = *(const h8v*)(vsr + (kk + 1) * 64 + g * 16);
      acc_e = mfma16(af[kk], vf0, acc_e);
      acc_o = mfma16(af[kk + 1], vf1, acc_o);
    }
    f4v y4 = acc_e + acc_o;           // every D-column equals y (B cols identical)
    // y = beta + 128 * (Wu·h - G·c)·2^-7 ; rows m = 4g+r -> i = wv*16+4g+r
#pragma unroll
    for (int r = 0; r < 4; ++r) {
      float y = beta4[r] + y4[r] * 128.f;
      float hv = fmaxf(y, 0.f);
      cm4[r] += hv;
      y4[r] = hv;                      // reuse as h storage
    }
    char* vsw = smem + VS_OFF + ((t + 1) & 1) * 2048;
    if (l15 == 0) {
      h4v hh, ch;
#pragma unroll
      for (int r = 0; r < 4; ++r) {
        hh[r] = (_Float16)(y4[r] * 0.0078125f);     //  h * 2^-7
        ch[r] = (_Float16)(-cm4[r] * 0.0078125f);   // -c * 2^-7
      }
      *(u64*)(vsw + vslot)       = __builtin_bit_cast(u64, hh);
      *(u64*)(vsw + 512 + vslot) = __builtin_bit_cast(u64, ch);
    }
    BAR();
  }
  if (l15 == 0)
    *(f4v*)(cout + (size_t)B * 256 + wv * 16 + 4 * g) = cm4;
}

extern "C" void kernel_launch(void* const* d_in, const int* in_sizes, int n_in,
                              void* d_out, int out_size, void* d_ws, size_t ws_size,
                              hipStream_t stream)
{
  const float* w  = (const float*)d_in[0];
  const float* b  = (const float*)d_in[1];
  const float* Ww = (const float*)d_in[2];
  const float* Wu = (const float*)d_in[3];
  const float* Wv = (const float*)d_in[4];

  char* ws = (char*)d_ws;
  float*    beta = (float*)(ws);
  float*    cbuf = (float*)(ws + (size_t)2 * 1024 * 1024);
  _Float16* wvp  = (_Float16*)(ws + (size_t)4 * 1024 * 1024);
  _Float16* wwp2 = (_Float16*)(ws + (size_t)4 * 1024 * 1024 + 131072);
  _Float16* wup  = (_Float16*)(ws + (size_t)4 * 1024 * 1024 + 262144);

  (void)in_sizes; (void)n_in; (void)out_size; (void)ws_size;

  hipFuncSetAttribute((const void*)fused_k,
                      hipFuncAttributeMaxDynamicSharedMemorySize, LDS_FUSED);

  prep_k<<<256, 256, 0, stream>>>(Wu, wup);
  prep2_k<<<256, 256, 0, stream>>>(Wv, Ww, wvp, wwp2);
  matvec_k<<<2048, 256, 0, stream>>>(Ww, b, beta);                  // beta = Ww @ b
  fused_k<<<2048, 1024, LDS_FUSED, stream>>>(w, wvp, wwp2, wup, beta, cbuf);
  matvec_k<<<2048, 256, 0, stream>>>(Wv, cbuf, (float*)d_out);      // x = Wv @ c
}

// Round 14
// 575.996 us; speedup vs baseline: 3.3720x; 1.1640x over previous
//
#include <hip/hip_runtime.h>

typedef _Float16 h2v __attribute__((ext_vector_type(2)));
typedef _Float16 h4v __attribute__((ext_vector_type(4)));
typedef _Float16 h8v __attribute__((ext_vector_type(8)));
typedef float    f4v __attribute__((ext_vector_type(4)));
typedef unsigned int u32;
typedef unsigned long long u64;

#define WUP_STRIDE 264        // wup padded row (halves)

// LDS layout (bytes) for fused_k (1024 threads)
// GEMM phase: WT0/WT1/TT/WWS0/WWS1 (84992 B) live inside the GC region
// (135168 B), which is written only after the last tau barrier.
#define WT_STRIDE 264         // halves per w-tile row (528 B)
#define WT0_OFF   0
#define WT1_OFF   16896       // 32*264*2
#define TT_OFF    33792       // 256 rows * 36 halves * 2 = 18432 -> end 52224
#define TT_STRIDE 36          // halves per Tt row (72 B)
#define WWS0_OFF  52224       // wwp2 tau-slice double buffer (2 x 16384)
#define WWS1_OFF  68608       // end 84992
#define GC_OFF    0           // full G 256 x 264 halves = 135168 B (after GEMM)
#define GC_STRIDE 264         // 528 B/row
#define VS_OFF    135168      // 2 x 2048 B
#define LDS_FUSED 139264

__device__ inline f4v mfma16(h8v a, h8v b, f4v c) {
  return __builtin_amdgcn_mfma_f32_16x16x32_f16(a, b, c, 0, 0, 0);
}

__device__ inline h8v cvt8(f4v lo, f4v hi) {
  h8v d;
  d[0] = (_Float16)lo[0]; d[1] = (_Float16)lo[1]; d[2] = (_Float16)lo[2]; d[3] = (_Float16)lo[3];
  d[4] = (_Float16)hi[0]; d[5] = (_Float16)hi[1]; d[6] = (_Float16)hi[2]; d[7] = (_Float16)hi[3];
  return d;
}

// raw barrier: LDS-visibility only, never drains vmcnt
#define BAR() { asm volatile("s_waitcnt lgkmcnt(0)" ::: "memory"); \
                __builtin_amdgcn_s_barrier(); \
                asm volatile("" ::: "memory"); }

// fragment loader: ROW-BASE pointer; kk/g offsets applied exactly once
#define LDH(basep, kk, dst) { \
    h4v lo_ = *(const h4v*)((basep) + (kk)*32 + 4*g); \
    h4v hi_ = *(const h4v*)((basep) + (kk)*32 + 16 + 4*g); \
    dst = __builtin_shufflevector(lo_, hi_, 0, 1, 2, 3, 4, 5, 6, 7); }

// ---- prep: Wu padded row-major (A-frag source for the recurrence) ----
__global__ void prep_k(const float* __restrict__ Wu, _Float16* __restrict__ wup)
{
  int j = blockIdx.x, k = threadIdx.x;
  wup[j * WUP_STRIDE + k] = (_Float16)Wu[j * 256 + k];
  if (k < 8) wup[j * WUP_STRIDE + 256 + k] = (_Float16)0.f;
}

// ---- prep2: pack Wv (wvp) and Ww (wwp2, t-sliced) into MFMA B-frag order ----
// koff(g,h) = h<4 ? 4g+h : 16+4g+(h-4)
// wvp [(nt*8+kk)*64+lane]*8+h  = Wv[kk*32+koff][nt*16+l15]
// wwp2[(tau*16+it)*64+lane]*8+h = Ww[it*16+l15][tau*32+koff]
__global__ void prep2_k(const float* __restrict__ Wv, const float* __restrict__ Ww,
                        _Float16* __restrict__ wvp, _Float16* __restrict__ wwp2)
{
  int b = blockIdx.x;
  int tid = threadIdx.x;
  int lane = tid & 63, q = tid >> 6;
  int g2 = (lane >> 4) & 3, l15 = lane & 15;
  if (b < 128) {
    int nt = b >> 3, kk = b & 7;
    int j = nt * 16 + l15;
    _Float16* dst = wvp + ((size_t)(b * 64 + lane)) * 8;
#pragma unroll
    for (int e = 0; e < 2; ++e) {
      int h = 2 * q + e;
      int k = kk * 32 + (h < 4 ? 4 * g2 + h : 16 + 4 * g2 + (h - 4));
      dst[h] = (_Float16)Wv[(size_t)k * 256 + j];
    }
  } else {
    int s = b - 128;                 // tau*16 + it
    int it = s & 15;
    int tau = s >> 4;
    int i = it * 16 + l15;
    _Float16* dst = wwp2 + ((size_t)(s * 64 + lane)) * 8;
#pragma unroll
    for (int e = 0; e < 2; ++e) {
      int h = 2 * q + e;
      int t = tau * 32 + (h < 4 ? 4 * g2 + h : 16 + 4 * g2 + (h - 4));
      dst[h] = (_Float16)Ww[(size_t)i * 256 + t];
    }
  }
}

// out[b,i] = sum_j M[i,j] * V[b,j]   (beta = Ww@b ; final x = Wv@c)
__global__ void matvec_k(const float* __restrict__ M, const float* __restrict__ V,
                         float* __restrict__ out)
{
  __shared__ float vb[256];
  int b = blockIdx.x, i = threadIdx.x;
  vb[i] = V[(size_t)b * 256 + i];
  __syncthreads();
  float a0 = 0.f;
#pragma unroll 8
  for (int j = 0; j < 256; j += 4) {
    f4v m = *(const f4v*)(M + (size_t)i * 256 + j);
    a0 += m[0] * vb[j] + m[1] * vb[j + 1] + m[2] * vb[j + 2] + m[3] * vb[j + 3];
  }
  out[(size_t)b * 256 + i] = a0;
}

// ================= fused (1024 thr, 16 waves, 1 batch/block) ================
// vs round 13: GEMM1 B-frags live in 32 regs (loaded once, all taus);
// GEMM2 B-frags staged per-tau into LDS (reg->LDS double buffer) and read by
// all waves from LDS -- removes the per-tau L2 fragment streaming that
// dominated the tau-loop. Recurrence (MFMA on [Wu|G]) unchanged.
__global__ __launch_bounds__(1024, 1) void fused_k(
    const float* __restrict__ w, const _Float16* __restrict__ wvp,
    const _Float16* __restrict__ wwp2, const _Float16* __restrict__ wup,
    const float* __restrict__ beta, float* __restrict__ cout)
{
  extern __shared__ char smem[];
  _Float16* const TT = (_Float16*)(smem + TT_OFF);

  const int tid = threadIdx.x;
  const int wv = tid >> 6, lane = tid & 63;
  const int g = (lane >> 4) & 3, l15 = lane & 15;
  const int st_t = tid >> 5;            // staging row 0..31
  const int st_c = (tid & 31) * 8;      // staging col base (floats)
  const int B   = blockIdx.x;
  const float* wb = w + (size_t)B * 65536;

  f4v sw[2];                            // staged w (next-next tile), 32B/thread
  uint4 sws;                            // staged wwp2 slice (next-next), 16B/thread

  // ---- GEMM1 B-frags: fixed per wave, loaded once, reused all taus ----
  h8v bfv[8];
#pragma unroll
  for (int kk = 0; kk < 8; ++kk)
    bfv[kk] = *(const h8v*)(wvp + ((size_t)((wv * 8 + kk) * 64 + lane)) * 8);

  // prologue: w tile0 -> wt[0]; wws slice0 -> WWS0; stage tile1/slice1 regs
  {
    const float* src0 = wb + (size_t)st_t * 256 + st_c;
    sw[0] = *(const f4v*)(src0);
    sw[1] = *(const f4v*)(src0 + 4);
    _Float16* dst = (_Float16*)(smem + WT0_OFF) + st_t * WT_STRIDE + st_c;
    *(h8v*)dst = cvt8(sw[0], sw[1]);
    *(uint4*)(smem + WWS0_OFF + tid * 16) =
        *(const uint4*)((const char*)wwp2 + tid * 16);
    const float* src1 = wb + (size_t)(32 + st_t) * 256 + st_c;
    sw[0] = *(const f4v*)(src1);
    sw[1] = *(const f4v*)(src1 + 4);
    sws = *(const uint4*)((const char*)wwp2 + 16384 + tid * 16);
    BAR();
  }

  f4v acc2[16];
#pragma unroll
  for (int it = 0; it < 16; ++it) acc2[it] = f4v{0.f, 0.f, 0.f, 0.f};

#pragma unroll 2
  for (int tau = 0; tau < 8; ++tau) {
    // A) write wt[(tau+1)&1] and wws[(tau+1)&1] from staged regs
    if (tau < 7) {
      _Float16* dst = (_Float16*)(smem + (((tau + 1) & 1) ? WT1_OFF : WT0_OFF))
                      + st_t * WT_STRIDE + st_c;
      *(h8v*)dst = cvt8(sw[0], sw[1]);
      *(uint4*)(smem + (((tau + 1) & 1) ? WWS1_OFF : WWS0_OFF) + tid * 16) = sws;
    }
    // B) issue loads for tau+2 (w tile + wws slice)
    if (tau < 6) {
      const float* src = wb + (size_t)((tau + 2) * 32 + st_t) * 256 + st_c;
      sw[0] = *(const f4v*)(src);
      sw[1] = *(const f4v*)(src + 4);
      sws = *(const uint4*)((const char*)wwp2 + (size_t)(tau + 2) * 16384 + tid * 16);
    }
    // C) GEMM1(tau): wave wv covers j = wv*16..wv*16+15 (B-frags in regs)
    f4v acc1[2];
    acc1[0] = f4v{0.f, 0.f, 0.f, 0.f};
    acc1[1] = f4v{0.f, 0.f, 0.f, 0.f};
    {
      const _Float16* wt = (const _Float16*)(smem + ((tau & 1) ? WT1_OFF : WT0_OFF));
#pragma unroll
      for (int kk = 0; kk < 8; ++kk) {
        h8v a0, a1;
        LDH(wt + (l15) * WT_STRIDE, kk, a0);            // t rows 0..15
        LDH(wt + (16 + l15) * WT_STRIDE, kk, a1);       // t rows 16..31
        acc1[0] = mfma16(a0, bfv[kk], acc1[0]);
        acc1[1] = mfma16(a1, bfv[kk], acc1[1]);
      }
    }
    // D) write Tt(tau): rows j = wv*16+l15 (wave-local), cols t
#pragma unroll
    for (int tm = 0; tm < 2; ++tm) {
      const int j = wv * 16 + l15;
      f4v a = acc1[tm];
      h4v t4; t4[0] = (_Float16)a[0]; t4[1] = (_Float16)a[1];
      t4[2] = (_Float16)a[2]; t4[3] = (_Float16)a[3];
      *(h4v*)(TT + j * TT_STRIDE + tm * 16 + g * 4) = t4;
    }
    // E) GEMM2(tau): acc2[it] += Tt(j-rows, t) * Ww(i, t)  (B-frags from LDS)
    {
      h8v a0;
      LDH(TT + (wv * 16 + l15) * TT_STRIDE, 0, a0);     // wave-local rows
      const char* wws = smem + ((tau & 1) ? WWS1_OFF : WWS0_OFF);
#pragma unroll
      for (int it = 0; it < 16; ++it) {
        h8v bf = *(const h8v*)(wws + (it * 64 + lane) * 16);
        acc2[it] = mfma16(a0, bf, acc2[it]);
      }
    }
    // F) one barrier per tau
    BAR();
  } // tau

  // ---- write FULL G into LDS (overlays WT/TT/WWS; GEMM reads done) ----
  // lane holds acc2[it] = G[j = wv*16 + g*4 + reg][i = it*16 + l15]
  {
    _Float16* const GC = (_Float16*)(smem + GC_OFF);
#pragma unroll
    for (int it = 0; it < 16; ++it) {
      const int i = it * 16 + l15;
      f4v a = acc2[it];
      h4v t4; t4[0] = (_Float16)a[0]; t4[1] = (_Float16)a[1];
      t4[2] = (_Float16)a[2]; t4[3] = (_Float16)a[3];
      *(h4v*)(GC + (size_t)i * GC_STRIDE + wv * 16 + g * 4) = t4;
    }
  }
  // zero VS buffer 0 (h=0, c=0)
  if (tid < 256) ((u64*)(smem + VS_OFF))[tid] = 0ull;
  BAR();   // G + VS0 visible

  // ---- load A-frags of [Wu | G] for this wave's 16-row i-tile ----
  h8v af[16];
  {
    const int arow = wv * 16 + l15;
    const _Float16* wurow = wup + (size_t)arow * WUP_STRIDE;
#pragma unroll
    for (int kk = 0; kk < 8; ++kk) { LDH(wurow, kk, af[kk]); }
    const _Float16* gcrow = (const _Float16*)(smem + GC_OFF) + (size_t)arow * GC_STRIDE;
#pragma unroll
    for (int kk = 0; kk < 8; ++kk) { LDH(gcrow, kk, af[8 + kk]); }
  }
  f4v beta4 = *(const f4v*)(beta + (size_t)B * 256 + wv * 16 + 4 * g);
  f4v cm4 = f4v{0.f, 0.f, 0.f, 0.f};

  // producer slot for this (wv,g): byte offset within VS h-part / c-part
  const int vslot = (wv >> 1) * 64 + g * 16 + (wv & 1) * 8;

  for (int t = 0; t < 20; ++t) {
    const char* vsr = smem + VS_OFF + (t & 1) * 2048;
    f4v acc_e = f4v{0.f, 0.f, 0.f, 0.f};
    f4v acc_o = f4v{0.f, 0.f, 0.f, 0.f};
#pragma unroll
    for (int kk = 0; kk < 16; kk += 2) {
      h8v vf0 = *(const h8v*)(vsr + kk * 64 + g * 16);
      h8v vf1 = *(const h8v*)(vsr + (kk + 1) * 64 + g * 16);
      acc_e = mfma16(af[kk], vf0, acc_e);
      acc_o = mfma16(af[kk + 1], vf1, acc_o);
    }
    f4v y4 = acc_e + acc_o;           // every D-column equals y (B cols identical)
#pragma unroll
    for (int r = 0; r < 4; ++r) {
      float y = beta4[r] + y4[r] * 128.f;
      float hv = fmaxf(y, 0.f);
      cm4[r] += hv;
      y4[r] = hv;                      // reuse as h storage
    }
    char* vsw = smem + VS_OFF + ((t + 1) & 1) * 2048;
    if (l15 == 0) {
      h4v hh, ch;
#pragma unroll
      for (int r = 0; r < 4; ++r) {
        hh[r] = (_Float16)(y4[r] * 0.0078125f);     //  h * 2^-7
        ch[r] = (_Float16)(-cm4[r] * 0.0078125f);   // -c * 2^-7
      }
      *(u64*)(vsw + vslot)       = __builtin_bit_cast(u64, hh);
      *(u64*)(vsw + 512 + vslot) = __builtin_bit_cast(u64, ch);
    }
    BAR();
  }
  if (l15 == 0)
    *(f4v*)(cout + (size_t)B * 256 + wv * 16 + 4 * g) = cm4;
}

extern "C" void kernel_launch(void* const* d_in, const int* in_sizes, int n_in,
                              void* d_out, int out_size, void* d_ws, size_t ws_size,
                              hipStream_t stream)
{
  const float* w  = (const float*)d_in[0];
  const float* b  = (const float*)d_in[1];
  const float* Ww = (const float*)d_in[2];
  const float* Wu = (const float*)d_in[3];
  const float* Wv = (const float*)d_in[4];

  char* ws = (char*)d_ws;
  float*    beta = (float*)(ws);
  float*    cbuf = (float*)(ws + (size_t)2 * 1024 * 1024);
  _Float16* wvp  = (_Float16*)(ws + (size_t)4 * 1024 * 1024);
  _Float16* wwp2 = (_Float16*)(ws + (size_t)4 * 1024 * 1024 + 131072);
  _Float16* wup  = (_Float16*)(ws + (size_t)4 * 1024 * 1024 + 262144);

  (void)in_sizes; (void)n_in; (void)out_size; (void)ws_size;

  hipFuncSetAttribute((const void*)fused_k,
                      hipFuncAttributeMaxDynamicSharedMemorySize, LDS_FUSED);

  prep_k<<<256, 256, 0, stream>>>(Wu, wup);
  prep2_k<<<256, 256, 0, stream>>>(Wv, Ww, wvp, wwp2);
  matvec_k<<<2048, 256, 0, stream>>>(Ww, b, beta);                  // beta = Ww @ b
  fused_k<<<2048, 1024, LDS_FUSED, stream>>>(w, wvp, wwp2, wup, beta, cbuf);
  matvec_k<<<2048, 256, 0, stream>>>(Wv, cbuf, (float*)d_out);      // x = Wv @ c
}

// Round 15
// 490.915 us; speedup vs baseline: 3.9564x; 1.1733x over previous
//
#include <hip/hip_runtime.h>

typedef _Float16 h2v __attribute__((ext_vector_type(2)));
typedef _Float16 h4v __attribute__((ext_vector_type(4)));
typedef _Float16 h8v __attribute__((ext_vector_type(8)));
typedef float    f4v __attribute__((ext_vector_type(4)));
typedef unsigned int u32;
typedef unsigned long long u64;

#define WUP_STRIDE 264        // wup padded row (halves)

// LDS layout (bytes) for fused_k (1024 threads)
// GEMM phase: WT(frag-order, dbuf) + TT(dbuf) + WWS(tribuf) = 119296 B,
// all inside the GC region (135168 B) which is written after the GEMMs.
#define WT_FRAG_STRIDE 1040   // 64 lanes*16B + 16B pad (bank spread)
#define WT_TILE   16640       // 16 frag blocks
#define WT0_OFF   0
#define WT1_OFF   16640
#define TT0_OFF   33280       // 256 rows * 36 halves * 2 = 18432
#define TT1_OFF   51712
#define TT_STRIDE 36
#define WWS0_OFF  70144       // 3 slices x 16384 -> end 119296
#define GC_OFF    0           // full G 256 x 264 halves = 135168 B
#define GC_STRIDE 264
#define VS_OFF    135168      // 2 x 2048 B
#define LDS_FUSED 139264

__device__ inline f4v mfma16(h8v a, h8v b, f4v c) {
  return __builtin_amdgcn_mfma_f32_16x16x32_f16(a, b, c, 0, 0, 0);
}

__device__ inline u64 cvt4(f4v v) {
  h4v d; d[0] = (_Float16)v[0]; d[1] = (_Float16)v[1];
  d[2] = (_Float16)v[2]; d[3] = (_Float16)v[3];
  return __builtin_bit_cast(u64, d);
}

// raw barrier: LDS-visibility only, never drains vmcnt
#define BAR() { asm volatile("s_waitcnt lgkmcnt(0)" ::: "memory"); \
                __builtin_amdgcn_s_barrier(); \
                asm volatile("" ::: "memory"); }

// fragment loader: ROW-BASE pointer; kk/g offsets applied exactly once
#define LDH(basep, kk, dst) { \
    h4v lo_ = *(const h4v*)((basep) + (kk)*32 + 4*g); \
    h4v hi_ = *(const h4v*)((basep) + (kk)*32 + 16 + 4*g); \
    dst = __builtin_shufflevector(lo_, hi_, 0, 1, 2, 3, 4, 5, 6, 7); }

// ---- prep: Wu padded row-major (A-frag source for the recurrence) ----
__global__ void prep_k(const float* __restrict__ Wu, _Float16* __restrict__ wup)
{
  int j = blockIdx.x, k = threadIdx.x;
  wup[j * WUP_STRIDE + k] = (_Float16)Wu[j * 256 + k];
  if (k < 8) wup[j * WUP_STRIDE + 256 + k] = (_Float16)0.f;
}

// ---- prep2: pack Wv (wvp) and Ww (wwp2, t-sliced) into MFMA B-frag order ----
// koff(g,h) = h<4 ? 4g+h : 16+4g+(h-4)
// wvp [(nt*8+kk)*64+lane]*8+h  = Wv[kk*32+koff][nt*16+l15]
// wwp2[(tau*16+it)*64+lane]*8+h = Ww[it*16+l15][tau*32+koff]
__global__ void prep2_k(const float* __restrict__ Wv, const float* __restrict__ Ww,
                        _Float16* __restrict__ wvp, _Float16* __restrict__ wwp2)
{
  int b = blockIdx.x;
  int tid = threadIdx.x;
  int lane = tid & 63, q = tid >> 6;
  int g2 = (lane >> 4) & 3, l15 = lane & 15;
  if (b < 128) {
    int nt = b >> 3, kk = b & 7;
    int j = nt * 16 + l15;
    _Float16* dst = wvp + ((size_t)(b * 64 + lane)) * 8;
#pragma unroll
    for (int e = 0; e < 2; ++e) {
      int h = 2 * q + e;
      int k = kk * 32 + (h < 4 ? 4 * g2 + h : 16 + 4 * g2 + (h - 4));
      dst[h] = (_Float16)Wv[(size_t)k * 256 + j];
    }
  } else {
    int s = b - 128;                 // tau*16 + it
    int it = s & 15;
    int tau = s >> 4;
    int i = it * 16 + l15;
    _Float16* dst = wwp2 + ((size_t)(s * 64 + lane)) * 8;
#pragma unroll
    for (int e = 0; e < 2; ++e) {
      int h = 2 * q + e;
      int t = tau * 32 + (h < 4 ? 4 * g2 + h : 16 + 4 * g2 + (h - 4));
      dst[h] = (_Float16)Ww[(size_t)i * 256 + t];
    }
  }
}

// out[b,i] = sum_j M[i,j] * V[b,j]   (beta = Ww@b ; final x = Wv@c)
__global__ void matvec_k(const float* __restrict__ M, const float* __restrict__ V,
                         float* __restrict__ out)
{
  __shared__ float vb[256];
  int b = blockIdx.x, i = threadIdx.x;
  vb[i] = V[(size_t)b * 256 + i];
  __syncthreads();
  float a0 = 0.f;
#pragma unroll 8
  for (int j = 0; j < 256; j += 4) {
    f4v m = *(const f4v*)(M + (size_t)i * 256 + j);
    a0 += m[0] * vb[j] + m[1] * vb[j + 1] + m[2] * vb[j + 2] + m[3] * vb[j + 3];
  }
  out[(size_t)b * 256 + i] = a0;
}

// ================= fused (1024 thr, 16 waves, 1 batch/block) ================
// vs round 14: (1) GEMM2 pipelined one tau behind GEMM1 (TT dbuf, WWS tribuf)
// -- within a phase the two GEMMs are independent, the TT produce->consume
// chain crosses a barrier where it is free; (2) WT stored in A-fragment order
// (contiguous b128 reads, no shufflevector); (3) recurrence 4 MFMA chains;
// (4) s_setprio around MFMA clusters.
__global__ __launch_bounds__(1024, 1) void fused_k(
    const float* __restrict__ w, const _Float16* __restrict__ wvp,
    const _Float16* __restrict__ wwp2, const _Float16* __restrict__ wup,
    const float* __restrict__ beta, float* __restrict__ cout)
{
  extern __shared__ char smem[];

  const int tid = threadIdx.x;
  const int wv = tid >> 6, lane = tid & 63;
  const int g = (lane >> 4) & 3, l15 = lane & 15;
  const int st_t = tid >> 5;            // staging row 0..31
  const int st_c = (tid & 31) * 8;      // staging col base (floats)
  const int B   = blockIdx.x;
  const float* wb = w + (size_t)B * 65536;

  // frag-order staging decomposition: thread (st_t, c) holds k = 8c..8c+7 of
  // row st_t; quad0 -> (g0, hb), quad1 -> (g0+1, hb). Verified mapping:
  // g0 = 2*(c&1), hb = 8*((c>>1)&1), kk = c>>2.
  const int c_   = tid & 31;
  const int wt_woff = ((c_ >> 2) * 2 + (st_t >> 4)) * WT_FRAG_STRIDE
                    + ((c_ & 1) * 32 + (st_t & 15)) * 16 + ((c_ >> 1) & 1) * 8;
#define WT_WRITE(off) { char* fb_ = smem + (off) + wt_woff; \
    *(u64*)fb_ = cvt4(sw[0]); *(u64*)(fb_ + 256) = cvt4(sw[1]); }

  f4v sw[2];                            // staged w (next-next tile)
  uint4 sws;                            // staged wwp2 slice (next-next)

  // ---- GEMM1 B-frags: fixed per wave, loaded once, reused all taus ----
  h8v bfv[8];
#pragma unroll
  for (int kk = 0; kk < 8; ++kk)
    bfv[kk] = *(const h8v*)(wvp + ((size_t)((wv * 8 + kk) * 64 + lane)) * 8);

  // prologue: w tile0 -> WT0; wws slice0 -> WWS0; reg-stage tile1/slice1
  {
    const float* src0 = wb + (size_t)st_t * 256 + st_c;
    sw[0] = *(const f4v*)(src0);
    sw[1] = *(const f4v*)(src0 + 4);
    WT_WRITE(WT0_OFF);
    *(uint4*)(smem + WWS0_OFF + tid * 16) =
        *(const uint4*)((const char*)wwp2 + tid * 16);
    const float* src1 = wb + (size_t)(32 + st_t) * 256 + st_c;
    sw[0] = *(const f4v*)(src1);
    sw[1] = *(const f4v*)(src1 + 4);
    sws = *(const uint4*)((const char*)wwp2 + 16384 + tid * 16);
    BAR();
  }

  f4v acc2[16];
#pragma unroll
  for (int it = 0; it < 16; ++it) acc2[it] = f4v{0.f, 0.f, 0.f, 0.f};

#pragma unroll
  for (int tau = 0; tau < 8; ++tau) {
    // A) write wt[(tau+1)&1] (frag order) and wws[(tau+1)%3] from staged regs
    if (tau < 7) {
      WT_WRITE(((tau + 1) & 1) ? WT1_OFF : WT0_OFF);
      *(uint4*)(smem + WWS0_OFF + ((tau + 1) % 3) * 16384 + tid * 16) = sws;
    }
    // B) issue loads for tau+2 (w tile + wws slice)
    if (tau < 6) {
      const float* src = wb + (size_t)((tau + 2) * 32 + st_t) * 256 + st_c;
      sw[0] = *(const f4v*)(src);
      sw[1] = *(const f4v*)(src + 4);
      sws = *(const uint4*)((const char*)wwp2 + (size_t)(tau + 2) * 16384 + tid * 16);
    }
    __builtin_amdgcn_s_setprio(1);
    // E) GEMM2(tau-1): acc2[it] += Tt(prev tau) * Ww  (independent of C/D)
    if (tau > 0) {
      const _Float16* ttr = (const _Float16*)(smem + (((tau - 1) & 1) ? TT1_OFF : TT0_OFF));
      h8v a0p; LDH(ttr + (wv * 16 + l15) * TT_STRIDE, 0, a0p);
      const char* wws = smem + WWS0_OFF + ((tau - 1) % 3) * 16384;
#pragma unroll
      for (int it = 0; it < 16; ++it) {
        h8v bf = *(const h8v*)(wws + (it * 64 + lane) * 16);
        acc2[it] = mfma16(a0p, bf, acc2[it]);
      }
    }
    // C) GEMM1(tau): contiguous b128 A-frag reads from frag-order WT
    f4v acc1[2];
    acc1[0] = f4v{0.f, 0.f, 0.f, 0.f};
    acc1[1] = f4v{0.f, 0.f, 0.f, 0.f};
    {
      const char* wtc = smem + ((tau & 1) ? WT1_OFF : WT0_OFF);
#pragma unroll
      for (int kk = 0; kk < 8; ++kk) {
        h8v a0 = *(const h8v*)(wtc + (kk * 2) * WT_FRAG_STRIDE + lane * 16);
        h8v a1 = *(const h8v*)(wtc + (kk * 2 + 1) * WT_FRAG_STRIDE + lane * 16);
        acc1[0] = mfma16(a0, bfv[kk], acc1[0]);
        acc1[1] = mfma16(a1, bfv[kk], acc1[1]);
      }
    }
    __builtin_amdgcn_s_setprio(0);
    // D) write Tt(tau) into TT[tau&1] (consumed by GEMM2 next phase)
    {
      _Float16* ttw = (_Float16*)(smem + ((tau & 1) ? TT1_OFF : TT0_OFF));
#pragma unroll
      for (int tm = 0; tm < 2; ++tm) {
        f4v a = acc1[tm];
        h4v t4; t4[0] = (_Float16)a[0]; t4[1] = (_Float16)a[1];
        t4[2] = (_Float16)a[2]; t4[3] = (_Float16)a[3];
        *(h4v*)(ttw + (wv * 16 + l15) * TT_STRIDE + tm * 16 + g * 4) = t4;
      }
    }
    // F) one barrier per tau
    BAR();
  } // tau

  // epilogue: GEMM2(7)
  {
    const _Float16* ttr = (const _Float16*)(smem + TT1_OFF);
    h8v a0p; LDH(ttr + (wv * 16 + l15) * TT_STRIDE, 0, a0p);
    const char* wws = smem + WWS0_OFF + (7 % 3) * 16384;
#pragma unroll
    for (int it = 0; it < 16; ++it) {
      h8v bf = *(const h8v*)(wws + (it * 64 + lane) * 16);
      acc2[it] = mfma16(a0p, bf, acc2[it]);
    }
  }
  BAR();   // all TT/WWS reads done before GC overlays them

  // ---- write FULL G into LDS ----
  // lane holds acc2[it] = G[j = wv*16 + g*4 + reg][i = it*16 + l15]
  {
    _Float16* const GC = (_Float16*)(smem + GC_OFF);
#pragma unroll
    for (int it = 0; it < 16; ++it) {
      const int i = it * 16 + l15;
      f4v a = acc2[it];
      h4v t4; t4[0] = (_Float16)a[0]; t4[1] = (_Float16)a[1];
      t4[2] = (_Float16)a[2]; t4[3] = (_Float16)a[3];
      *(h4v*)(GC + (size_t)i * GC_STRIDE + wv * 16 + g * 4) = t4;
    }
  }
  // zero VS buffer 0 (h=0, c=0)
  if (tid < 256) ((u64*)(smem + VS_OFF))[tid] = 0ull;
  BAR();   // G + VS0 visible

  // ---- load A-frags of [Wu | G] for this wave's 16-row i-tile ----
  h8v af[16];
  {
    const int arow = wv * 16 + l15;
    const _Float16* wurow = wup + (size_t)arow * WUP_STRIDE;
#pragma unroll
    for (int kk = 0; kk < 8; ++kk) { LDH(wurow, kk, af[kk]); }
    const _Float16* gcrow = (const _Float16*)(smem + GC_OFF) + (size_t)arow * GC_STRIDE;
#pragma unroll
    for (int kk = 0; kk < 8; ++kk) { LDH(gcrow, kk, af[8 + kk]); }
  }
  f4v beta4 = *(const f4v*)(beta + (size_t)B * 256 + wv * 16 + 4 * g);
  f4v cm4 = f4v{0.f, 0.f, 0.f, 0.f};

  // producer slot for this (wv,g): byte offset within VS h-part / c-part
  const int vslot = (wv >> 1) * 64 + g * 16 + (wv & 1) * 8;

  for (int t = 0; t < 20; ++t) {
    const char* vsr = smem + VS_OFF + (t & 1) * 2048;
    f4v c0 = f4v{0.f, 0.f, 0.f, 0.f}, c1 = f4v{0.f, 0.f, 0.f, 0.f};
    f4v c2 = f4v{0.f, 0.f, 0.f, 0.f}, c3 = f4v{0.f, 0.f, 0.f, 0.f};
    __builtin_amdgcn_s_setprio(1);
#pragma unroll
    for (int kk = 0; kk < 16; kk += 4) {
      h8v v0 = *(const h8v*)(vsr + kk * 64 + g * 16);
      h8v v1 = *(const h8v*)(vsr + (kk + 1) * 64 + g * 16);
      h8v v2 = *(const h8v*)(vsr + (kk + 2) * 64 + g * 16);
      h8v v3 = *(const h8v*)(vsr + (kk + 3) * 64 + g * 16);
      c0 = mfma16(af[kk], v0, c0);
      c1 = mfma16(af[kk + 1], v1, c1);
      c2 = mfma16(af[kk + 2], v2, c2);
      c3 = mfma16(af[kk + 3], v3, c3);
    }
    __builtin_amdgcn_s_setprio(0);
    f4v y4 = (c0 + c1) + (c2 + c3);   // every D-column equals y
#pragma unroll
    for (int r = 0; r < 4; ++r) {
      float y = beta4[r] + y4[r] * 128.f;
      float hv = fmaxf(y, 0.f);
      cm4[r] += hv;
      y4[r] = hv;                      // reuse as h storage
    }
    char* vsw = smem + VS_OFF + ((t + 1) & 1) * 2048;
    if (l15 == 0) {
      h4v hh, ch;
#pragma unroll
      for (int r = 0; r < 4; ++r) {
        hh[r] = (_Float16)(y4[r] * 0.0078125f);     //  h * 2^-7
        ch[r] = (_Float16)(-cm4[r] * 0.0078125f);   // -c * 2^-7
      }
      *(u64*)(vsw + vslot)       = __builtin_bit_cast(u64, hh);
      *(u64*)(vsw + 512 + vslot) = __builtin_bit_cast(u64, ch);
    }
    BAR();
  }
  if (l15 == 0)
    *(f4v*)(cout + (size_t)B * 256 + wv * 16 + 4 * g) = cm4;
}

extern "C" void kernel_launch(void* const* d_in, const int* in_sizes, int n_in,
                              void* d_out, int out_size, void* d_ws, size_t ws_size,
                              hipStream_t stream)
{
  const float* w  = (const float*)d_in[0];
  const float* b  = (const float*)d_in[1];
  const float* Ww = (const float*)d_in[2];
  const float* Wu = (const float*)d_in[3];
  const float* Wv = (const float*)d_in[4];

  char* ws = (char*)d_ws;
  float*    beta = (float*)(ws);
  float*    cbuf = (float*)(ws + (size_t)2 * 1024 * 1024);
  _Float16* wvp  = (_Float16*)(ws + (size_t)4 * 1024 * 1024);
  _Float16* wwp2 = (_Float16*)(ws + (size_t)4 * 1024 * 1024 + 131072);
  _Float16* wup  = (_Float16*)(ws + (size_t)4 * 1024 * 1024 + 262144);

  (void)in_sizes; (void)n_in; (void)out_size; (void)ws_size;

  hipFuncSetAttribute((const void*)fused_k,
                      hipFuncAttributeMaxDynamicSharedMemorySize, LDS_FUSED);

  prep_k<<<256, 256, 0, stream>>>(Wu, wup);
  prep2_k<<<256, 256, 0, stream>>>(Wv, Ww, wvp, wwp2);
  matvec_k<<<2048, 256, 0, stream>>>(Ww, b, beta);                  // beta = Ww @ b
  fused_k<<<2048, 1024, LDS_FUSED, stream>>>(w, wvp, wwp2, wup, beta, cbuf);
  matvec_k<<<2048, 256, 0, stream>>>(Wv, cbuf, (float*)d_out);      // x = Wv @ c
}